// Round 6
// baseline (721.898 us; speedup 1.0000x reference)
//
#include <hip/hip_runtime.h>
#include <math.h>

typedef unsigned short u16;
typedef unsigned int   u32;
typedef __attribute__((ext_vector_type(2))) _Float16 half2_t;

#define B_   32
#define S_   200
#define D_   128
#define T_   199
#define NEGV (-1e30f)

__device__ __forceinline__ float bf2f(u16 u){
  union { u32 i; float f; } v; v.i = ((u32)u) << 16; return v.f;
}
__device__ __forceinline__ u16 f2bf(float f){
  union { float f; u32 i; } v; v.f = f;
  u32 x = v.i;
  return (u16)((x + 0x7fffu + ((x >> 16) & 1u)) >> 16);   // RNE
}
__device__ __forceinline__ u16 f2h(float x){
  union { _Float16 h; u16 u; } v; v.h = (_Float16)x; return v.u;
}
__device__ __forceinline__ float h2f(u16 u){
  union { u16 u; _Float16 h; } v; v.u = u; return (float)v.h;
}
__device__ __forceinline__ u32 pkh(float lo, float hi){
  return ((u32)f2h(hi) << 16) | f2h(lo);
}
// 2 MACs/instr: f32 += f16x2 . f16x2  (v_dot2_f32_f16)
__device__ __forceinline__ float dot2f(u32 w, u32 h, float acc){
#if __has_builtin(__builtin_amdgcn_fdot2)
  union { u32 u; half2_t h2; } a, b;
  a.u = w; b.u = h;
  return __builtin_amdgcn_fdot2(a.h2, b.h2, acc, false);
#else
  union { u32 u; _Float16 f[2]; } a, b;
  a.u = w; b.u = h;
  acc = fmaf((float)a.f[0], (float)b.f[0], acc);
  return fmaf((float)a.f[1], (float)b.f[1], acc);
#endif
}
__device__ __forceinline__ float fast_sigmoid(float x){ return 1.f/(1.f+__expf(-x)); }
__device__ __forceinline__ float fast_tanh(float x){
  float e = __expf(2.f*x);
  return 1.f - 2.f/(e + 1.f);
}

// Raw barrier: drains LDS ops only, NOT vmcnt. __syncthreads would force
// s_waitcnt vmcnt(0) and kill the cross-step global prefetch / store overlap.
#define BARX() asm volatile("s_waitcnt lgkmcnt(0)\n\ts_barrier" ::: "memory")

// Keep a loaded value opaque (no rematerialization across the asm).
#define PINV(x) asm volatile("" : "+v"(x))

// quad-lane butterfly add via DPP (VALU, no LDS): v += v[lane^k], k=1 or 2
template<int CTRL>
__device__ __forceinline__ float dppadd(float v){
  union { float f; int i; } a, r;
  a.f = v;
  r.i = __builtin_amdgcn_mov_dpp(a.i, CTRL, 0xF, 0xF, true);
  return v + r.f;
}
#define DPP_XOR1 0xB1   // quad_perm [1,0,3,2]
#define DPP_XOR2 0x4E   // quad_perm [2,3,0,1]

// bool storage modes: 0=int32, 1=u8, 2=bf16, 3=f32
__device__ __forceinline__ int readBool(const void* p, int i, int m){
  if (m == 0) return ((const int*)p)[i] != 0;
  if (m == 1) return ((const unsigned char*)p)[i] != 0;
  if (m == 2) return ((const u16*)p)[i] != 0;
  return ((const u32*)p)[i] != 0;
}

__device__ __forceinline__ float dot128f(const float* __restrict__ w,
                                         const float* __restrict__ x){
  float acc = 0.f;
  const float4* wp = (const float4*)w;
  #pragma unroll 8
  for (int i = 0; i < 32; i++){
    float4 v = wp[i]; int k = 4*i;
    acc = fmaf(v.x, x[k],   acc);
    acc = fmaf(v.y, x[k+1], acc);
    acc = fmaf(v.z, x[k+2], acc);
    acc = fmaf(v.w, x[k+3], acc);
  }
  return acc;
}

// ---------------------------------------------------------------- sniffer
__global__ void k_sniff2(const u16* __restrict__ embq_raw,
                         const unsigned char* __restrict__ mask_raw,
                         int* __restrict__ flags){
  __shared__ int bad, gt1, m4, b0;
  const int tid = threadIdx.x;
  if (tid == 0){ bad = 0; gt1 = 0; m4 = 0; b0 = 0; }
  __syncthreads();
  for (int i = tid; i < 512; i += 256){
    u16 u = embq_raw[i];
    if (u){ int e = (u >> 7) & 0xFF; if (e < 0x58 || e > 0x7F) atomicAdd(&bad, 1); }
  }
  for (int i = tid; i < 1024; i += 256){
    unsigned char c = mask_raw[i];
    if (c > 1) atomicAdd(&gt1, 1);
    if (c && (i & 3)) atomicAdd(&m4, 1);
    if (c && !(i & 3)) atomicAdd(&b0, 1);
  }
  __syncthreads();
  if (tid == 0){
    flags[0] = (bad >= 16) ? 1 : 0;
    flags[1] = gt1 ? (b0 ? 2 : 3) : (m4 ? 1 : 0);
  }
}

// ---------------------------------------------------------------- convert floats -> f32
#define NCVT 23
struct CvtArgs { const void* s[NCVT]; int off[NCVT+1]; int nreal[NCVT]; };

__global__ void k_cvt(CvtArgs a, const int* __restrict__ flags, float* __restrict__ dst){
  __shared__ int f;
  if (threadIdx.x == 0) f = flags[0];
  __syncthreads();
  int gid = blockIdx.x * 256 + threadIdx.x;
  if (gid >= a.off[NCVT]) return;
  int ai = 0;
  for (int i = 1; i < NCVT; i++) if (gid >= a.off[i]) ai = i;
  int i = gid - a.off[ai];
  float v = 0.f;
  if (i < a.nreal[ai])
    v = f ? ((const float*)a.s[ai])[i] : bf2f(((const u16*)a.s[ai])[i]);
  dst[gid] = v;
}

// ---------------------------------------------------------------- prep
// W3: fused-chain weight pack, thread-major so the kernel's 24 uint4 loads
// are lane-consecutive (coalesced). Thread tid of k_chain12 owns the 3
// gate-rows (r,z,n) of outputs {2p,2p+1} of one family at K-quarter qt:
//   tid<256:  family A=WHH1, p=tid>>2, qt=tid&3
//   tid>=256: j=tid-256, p=j>>3, qt=j&3, fam=(j>>2)&1 -> WIH2 (C) / WHH2 (D)
// W3[(i*768)+tid] (uint4), i = row_local*4+g; row = 2p+(rl&1)+(rl>>1)*128;
// k = qt*32 + g*8 (+comp*2 within the uint4).
__global__ void k_prep(const float* __restrict__ WHH1, const float* __restrict__ WHH2,
                       const float* __restrict__ AW,   const float* __restrict__ ALW,
                       const float* __restrict__ WIH1, const float* __restrict__ WIH2,
                       const float* __restrict__ QW,
                       u32* __restrict__ W3,
                       u32* __restrict__ AWt,   u32* __restrict__ ALWt,
                       u32* __restrict__ WIH1t, float* __restrict__ QWt)
{
  const int gid0 = blockIdx.x*256 + threadIdx.x;
  const int stride = gridDim.x*256;
  // W3: 73728 u32
  for (int w = gid0; w < 73728; w += stride){
    int v = w >> 2, comp = w & 3;
    int i = v / 768, tid = v - i*768;       // i in [0,24)
    int rl = i >> 2, g = i & 3;
    int p, qt; const float* mat;
    if (tid < 256){ p = tid >> 2; qt = tid & 3; mat = WHH1; }
    else {
      int j = tid - 256; p = j >> 3; qt = j & 3;
      mat = ((j >> 2) & 1) ? WHH2 : WIH2;
    }
    int row = 2*p + (rl & 1) + (rl >> 1)*128;
    int k = qt*32 + g*8 + comp*2;
    W3[w] = pkh(mat[row*128 + k], mat[row*128 + k + 1]);
  }
  // AW: 3 stages of 128x128 -> 8192 u32/stage
  for (int g = gid0; g < 24576; g += stride){
    int s = g >> 13, w = g & 8191;
    int k8 = w >> 9, r = w & 511, c = r >> 2, j = r & 3;
    const float* b = AW + s*16384 + c*128 + k8*8 + 2*j;
    AWt[g] = pkh(b[0], b[1]);
  }
  // ALW: 128x128
  for (int g = gid0; g < 8192; g += stride){
    int k8 = g >> 9, r = g & 511, c = r >> 2, j = r & 3;
    const float* b = ALW + c*128 + k8*8 + 2*j;
    ALWt[g] = pkh(b[0], b[1]);
  }
  // WIH1: 384x256 -> 32 groups x 1536
  for (int g = gid0; g < 49152; g += stride){
    int k8 = g / 1536, r = g % 1536, c = r >> 2, j = r & 3;
    const float* b = WIH1 + c*256 + k8*8 + 2*j;
    WIH1t[g] = pkh(b[0], b[1]);
  }
  // QW: 128x128 f32 -> float4 column layout (32 groups of 4 k)
  for (int g = gid0; g < 16384; g += stride){
    int k4 = g >> 9, r = g & 511, c = r >> 2, j = r & 3;
    QWt[g] = QW[c*128 + k4*4 + j];
  }
}

// ---------------------------------------------------------------- K1: hop aggregation (f16 dot2, coalesced Wt)
template<int ROWS>
__device__ __forceinline__ void agg_stage_h(const u16* __restrict__ tmph,
    const u32* __restrict__ Wt, const float* __restrict__ bg,
    u16* __restrict__ outh, int c)
{
  float bias = bg[c];
  float acc[ROWS];
  #pragma unroll
  for (int r = 0; r < ROWS; r++) acc[r] = bias;
  const uint4* wp = (const uint4*)Wt;
  if constexpr (ROWS <= 4){
    float acc2[ROWS];
    #pragma unroll
    for (int r = 0; r < ROWS; r++) acc2[r] = 0.f;
    #pragma unroll 4
    for (int g = 0; g < 16; g++){
      uint4 wv = wp[g*128 + c];          // coalesced: lanes consecutive
      #pragma unroll
      for (int r = 0; r < ROWS; r++){
        uint4 hv = *(const uint4*)(tmph + r*128 + g*8);   // LDS broadcast
        acc[r]  = dot2f(wv.x, hv.x, acc[r]);
        acc2[r] = dot2f(wv.y, hv.y, acc2[r]);
        acc[r]  = dot2f(wv.z, hv.z, acc[r]);
        acc2[r] = dot2f(wv.w, hv.w, acc2[r]);
      }
    }
    #pragma unroll
    for (int r = 0; r < ROWS; r++)
      outh[r*128 + c] = f2h(fast_tanh(acc[r] + acc2[r]));
  } else {
    #pragma unroll 4
    for (int g = 0; g < 16; g++){
      uint4 wv = wp[g*128 + c];
      #pragma unroll
      for (int r = 0; r < ROWS; r++){
        uint4 hv = *(const uint4*)(tmph + r*128 + g*8);
        acc[r] = dot2f(wv.x, hv.x, acc[r]);
        acc[r] = dot2f(wv.y, hv.y, acc[r]);
        acc[r] = dot2f(wv.z, hv.z, acc[r]);
        acc[r] = dot2f(wv.w, hv.w, acc[r]);
      }
    }
    #pragma unroll
    for (int r = 0; r < ROWS; r++)
      outh[r*128 + c] = f2h(fast_tanh(acc[r]));
  }
}

__launch_bounds__(256, 4)
__global__ void k_agg(const int* __restrict__ question,
                      const int* __restrict__ q_neighbors,
                      const int* __restrict__ s_neighbors,
                      const float* __restrict__ EQ,
                      const float* __restrict__ EC,
                      const u32* __restrict__ AWt,
                      const float* __restrict__ AB,
                      const u32* __restrict__ ALWt,
                      const float* __restrict__ ALB,
                      const void* __restrict__ maskp,
                      const int* __restrict__ flags,
                      float* __restrict__ EQREC)
{
  __shared__ __align__(16) u16 e0h[2][128];
  __shared__ __align__(16) u16 e1h[2][512];
  __shared__ __align__(16) u16 e2h[2][2048];
  __shared__ __align__(16) u16 tmph[2][2048];
  __shared__ int nn1[2][4]; __shared__ int nn2[2][16]; __shared__ int nn3[2][64];
  const int tid  = threadIdx.x;
  const int c    = tid & 127;
  const int half = tid >> 7;
  const int bs   = blockIdx.x*2 + half;
  const int n0   = question[bs];
  u16* tp = tmph[half];

  if (c < 4) nn1[half][c] = q_neighbors[n0*4 + c];
  __syncthreads();
  if (c < 16) nn2[half][c] = s_neighbors[nn1[half][c>>2]*4 + (c&3)];
  __syncthreads();
  if (c < 64) nn3[half][c] = q_neighbors[nn2[half][c>>2]*4 + (c&3)];
  e0h[half][c] = f2h(EQ[n0*128 + c]);
  #pragma unroll
  for (int r = 0; r < 4; r++)  e1h[half][r*128 + c] = f2h(EC[nn1[half][r]*128 + c]);
  #pragma unroll 4
  for (int r = 0; r < 16; r++) e2h[half][r*128 + c] = f2h(EQ[nn2[half][r]*128 + c]);
  __syncthreads();

  auto fill_e0 = [&](){
    float v = 0.25f*(h2f(e1h[half][c]) + h2f(e1h[half][128+c])
                   + h2f(e1h[half][256+c]) + h2f(e1h[half][384+c]))
            + h2f(e0h[half][c]);
    tp[c] = f2h(v);
  };
  auto fill_e1 = [&](){
    #pragma unroll
    for (int r = 0; r < 4; r++){
      float v = 0.25f*(h2f(e2h[half][(4*r)*128+c])   + h2f(e2h[half][(4*r+1)*128+c])
                     + h2f(e2h[half][(4*r+2)*128+c]) + h2f(e2h[half][(4*r+3)*128+c]))
              + h2f(e1h[half][r*128 + c]);
      tp[r*128 + c] = f2h(v);
    }
  };

  // i=0: j=0,1,2
  fill_e0(); __syncthreads();
  agg_stage_h<1>(tp, AWt, AB, e0h[half], c); __syncthreads();
  fill_e1(); __syncthreads();
  agg_stage_h<4>(tp, AWt + 8192, AB + 128, e1h[half], c); __syncthreads();
  #pragma unroll 2
  for (int r = 0; r < 16; r++){
    float m = 0.25f*( EC[nn3[half][4*r]*128+c]   + EC[nn3[half][4*r+1]*128+c]
                    + EC[nn3[half][4*r+2]*128+c] + EC[nn3[half][4*r+3]*128+c] );
    tp[r*128 + c] = f2h(m + h2f(e2h[half][r*128 + c]));
  }
  __syncthreads();
  agg_stage_h<16>(tp, AWt + 16384, AB + 256, e2h[half], c); __syncthreads();
  // i=1: j=0,1
  fill_e0(); __syncthreads();
  agg_stage_h<1>(tp, AWt, AB, e0h[half], c); __syncthreads();
  fill_e1(); __syncthreads();
  agg_stage_h<4>(tp, AWt + 8192, AB + 128, e1h[half], c); __syncthreads();
  // i=2: j=0
  fill_e0(); __syncthreads();
  agg_stage_h<1>(tp, AWt, AB, e0h[half], c); __syncthreads();
  // agg = tanh(e0 @ ALW.T + ALB)
  agg_stage_h<1>(e0h[half], ALWt, ALB, tp, c); __syncthreads();
  const int msk = readBool(maskp, bs, flags[1]);
  EQREC[bs*128 + c] = msk ? h2f(tp[c]) : EQ[n0*128 + c];
}

// ---------------------------------------------------------------- K2: gi1 precompute (K=256, f16 dot2, coalesced)
__launch_bounds__(384, 1)
__global__ void k_gi1(const float* __restrict__ EQREC,
                      const int* __restrict__ response,
                      const float* __restrict__ ECOR,
                      const u32* __restrict__ WIH1t,
                      const float* __restrict__ BIH1,
                      float* __restrict__ GI1)
{
  const int t  = blockIdx.x;
  const int bg = blockIdx.y;
  const int tid = threadIdx.x;
  __shared__ __align__(16) u16 X[8][256];
  for (int o = tid; o < 2048; o += 384){
    int bb = o >> 8, k = o & 255;
    int b = bg*8 + bb;
    float v = (k < 128) ? EQREC[(b*S_ + t)*128 + k]
                        : ECOR[response[b*S_ + t]*128 + (k - 128)];
    X[bb][k] = f2h(v);
  }
  __syncthreads();
  float bias = BIH1[tid];
  float acc[8];
  #pragma unroll
  for (int i = 0; i < 8; i++) acc[i] = bias;
  const uint4* wp = (const uint4*)WIH1t;   // 32 groups x 384
  #pragma unroll 4
  for (int g = 0; g < 32; g++){
    uint4 wv = wp[g*384 + tid];            // coalesced
    #pragma unroll
    for (int bb = 0; bb < 8; bb++){
      uint4 hv = *(const uint4*)(&X[bb][g*8]);   // broadcast
      acc[bb] = dot2f(wv.x, hv.x, acc[bb]);
      acc[bb] = dot2f(wv.y, hv.y, acc[bb]);
      acc[bb] = dot2f(wv.z, hv.z, acc[bb]);
      acc[bb] = dot2f(wv.w, hv.w, acc[bb]);
    }
  }
  #pragma unroll
  for (int bb = 0; bb < 8; bb++)
    GI1[(t*32 + bg*8 + bb)*384 + tid] = acc[bb];
}

// ---------------------------------------------------------------- K3: scores + top-10
__global__ void k_topk(const int* __restrict__ question,
                       const float* __restrict__ EQ,
                       int* __restrict__ IDX)
{
  const int blk = blockIdx.x;
  const int t = blk >> 5, b = blk & 31;
  const int tid = threadIdx.x;               // 64
  __shared__ __align__(16) float qn[128];
  const int qid = question[b*S_ + t + 1];
  for (int o = tid; o < 128; o += 64) qn[o] = EQ[qid*128 + o];
  __syncthreads();
  float val[4]; int sv[4];
  #pragma unroll
  for (int i = 0; i < 4; i++){
    int s = tid + 64*i;
    sv[i] = s;
    float v = -3.0e38f;
    if (s < S_) v = (s < t) ? dot128f(EQ + question[b*S_ + s]*128, qn) : NEGV;
    val[i] = v;
  }
  for (int r = 0; r < 10; r++){
    float bv = -3.0e38f; int bi = 0x3fffffff;
    #pragma unroll
    for (int i = 0; i < 4; i++){
      if (val[i] > bv || (val[i] == bv && sv[i] < bi)){ bv = val[i]; bi = sv[i]; }
    }
    for (int off = 32; off; off >>= 1){
      float ov = __shfl_down(bv, off);
      int   oi = __shfl_down(bi, off);
      if (ov > bv || (ov == bv && oi < bi)){ bv = ov; bi = oi; }
    }
    int win = __shfl(bi, 0);
    if (tid == 0) IDX[blk*10 + r] = win;
    #pragma unroll
    for (int i = 0; i < 4; i++) if (sv[i] == win) val[i] = -3.0e38f;
  }
}

// ---------------------------------------------------------------- K4: FUSED h1/h2 recurrence
// Quarter-K tasks + in-wave combine; ZERO LDS partial traffic.
// 768 threads = 12 waves. Thread = 3 gate-rows (r,z,n) of outputs {2p,2p+1}
// of one family at K-quarter qt (32 f16): 4 uniform-ish ds_read_b128 (64B
// ingestion, half of round-5) + 96 dot2. K-quarters on adjacent lanes ->
// combine via DPP quad_perm (xor1,xor2 = pure VALU). GRU2's C/D families on
// lane^4 -> one __shfl_xor(4). The combining lane then holds ALL GRU inputs
// in registers: update computed in phase 1 (overlapped with other waves'
// matvec); phase 2 is just two u32 LDS writes + float2 G2 store.
// LDS h layout hhx[4][88] u16 (chunks: h1lo,h1hi,h2lo,h2hi; 176B stride):
// the 8 distinct (chunk,quarter) 64B windows map to 8 distinct banks -> no
// conflict. 2 raw barriers/step; vmcnt never drained in-loop.
__launch_bounds__(768, 3)
__global__ void k_chain12(const float* __restrict__ GI1,
                          const uint4* __restrict__ W3,
                          const float* __restrict__ BHH1,
                          const float* __restrict__ BIH2,
                          const float* __restrict__ BHH2,
                          const float* __restrict__ H1I, const float* __restrict__ H2I,
                          float* __restrict__ G2)
{
  const int b   = blockIdx.x;
  const int tid = threadIdx.x;
  __shared__ __align__(16) u16 hhx[4][88];   // data in [0,64) of each chunk

  const int isA = (tid < 256);               // wave-uniform
  int p, qt, fam;
  if (isA){ p = tid >> 2; qt = tid & 3; fam = 0; }
  else { int j = tid - 256; p = j >> 3; qt = j & 3; fam = (j >> 2) & 1; }
  const int o0 = 2*p;

  // weights: 24 coalesced uint4 loads (96 VGPRs), pinned resident
  uint4 W[24];
  #pragma unroll
  for (int i = 0; i < 24; i++) W[i] = W3[i*768 + tid];
  #pragma unroll
  for (int i = 0; i < 24; i++){
    PINV(W[i].x); PINV(W[i].y); PINV(W[i].z); PINV(W[i].w);
  }

  // biases folded into qt==0 lanes' acc init (counted once after K-combine)
  float bs0[6];
  {
    const float* BP = isA ? BHH1 : (fam ? BHH2 : BIH2);
    #pragma unroll
    for (int rl = 0; rl < 6; rl++){
      int row = o0 + (rl & 1) + (rl >> 1)*128;
      bs0[rl] = (qt == 0) ? BP[row] : 0.f;
    }
  }

  // per-lane LDS h window
  const int csrc = ((!isA) && fam) ? 2 : 0;
  const u16* hb = &hhx[csrc + (qt >> 1)][(qt & 1)*32];

  const int leadA = isA && (qt == 0);
  const int leadG = (!isA) && (((tid - 256) & 7) == 0);

  float h1c0=0,h1c1=0,h2c0=0,h2c1=0;
  float pr0=0,pr1=0,pz0=0,pz1=0,pn0=0,pn1=0;     // pc = gi1(t+1), leadA lanes
  if (leadA){
    float2 h = *(const float2*)&H1I[b*128 + o0];
    h1c0 = h.x; h1c1 = h.y;
    const float* gp = GI1 + b*384;               // gi1(0)
    float2 r = *(const float2*)&gp[o0];
    float2 z = *(const float2*)&gp[128 + o0];
    float2 n = *(const float2*)&gp[256 + o0];
    pr0=r.x; pr1=r.y; pz0=z.x; pz1=z.y; pn0=n.x; pn1=n.y;
  }
  if (leadG){
    float2 h = *(const float2*)&H2I[b*128 + o0];
    h2c0 = h.x; h2c1 = h.y;
  }

  // init hhx
  if (tid < 128){
    hhx[tid >> 6][tid & 63] = f2h(H1I[b*128 + tid]);
  } else if (tid < 256){
    int u = tid - 128;
    hhx[2 + (u >> 6)][u & 63] = f2h(H2I[b*128 + u]);
  }
  BARX();

  float ac[6];
  auto mv = [&](){
    #pragma unroll
    for (int rl = 0; rl < 6; rl++) ac[rl] = bs0[rl];
    #pragma unroll
    for (int g = 0; g < 4; g++){
      uint4 hv = *(const uint4*)(hb + g*8);
      #pragma unroll
      for (int rl = 0; rl < 6; rl++){
        uint4 w = W[rl*4 + g];
        ac[rl] = dot2f(w.x, hv.x, ac[rl]);
        ac[rl] = dot2f(w.y, hv.y, ac[rl]);
        ac[rl] = dot2f(w.z, hv.z, ac[rl]);
        ac[rl] = dot2f(w.w, hv.w, ac[rl]);
      }
    }
    // K-combine across the 4 quarter-lanes (VALU only)
    #pragma unroll
    for (int rl = 0; rl < 6; rl++){
      ac[rl] = dppadd<DPP_XOR1>(ac[rl]);
      ac[rl] = dppadd<DPP_XOR2>(ac[rl]);
    }
  };

  // ---- prologue: h1(1) = gru1(x0, h1(0)); C/D results discarded
  mv();
  u32 hwv = 0;
  if (leadA){
    float r0 = fast_sigmoid(pr0 + ac[0]);
    float r1 = fast_sigmoid(pr1 + ac[1]);
    float z0 = fast_sigmoid(pz0 + ac[2]);
    float z1 = fast_sigmoid(pz1 + ac[3]);
    float n0 = fast_tanh(pn0 + r0*ac[4]);
    float n1 = fast_tanh(pn1 + r1*ac[5]);
    h1c0 = (1.f - z0)*n0 + z0*h1c0;
    h1c1 = (1.f - z1)*n1 + z1*h1c1;
    hwv = pkh(h1c0, h1c1);
  }
  BARX();
  if (leadA){
    *(u32*)&hhx[o0 >> 6][o0 & 63] = hwv;
    const float* gp = GI1 + (32 + b)*384;        // gi1(1)
    float2 r = *(const float2*)&gp[o0];
    float2 z = *(const float2*)&gp[128 + o0];
    float2 n = *(const float2*)&gp[256 + o0];
    pr0=r.x; pr1=r.y; pz0=z.x; pz1=z.y; pn0=n.x; pn1=n.y;
  }
  BARX();

  // ---- main loop
  #pragma unroll 1
  for (int t = 0; t < T_; t++){
    // prefetch gi1(t+2), consumed next iteration
    float qr0=0,qr1=0,qz0=0,qz1=0,qn0=0,qn1=0;
    if (leadA){
      int tp = (t + 2 < T_) ? t + 2 : T_ - 1;
      const float* gp = GI1 + (tp*32 + b)*384;
      float2 r = *(const float2*)&gp[o0];
      float2 z = *(const float2*)&gp[128 + o0];
      float2 n = *(const float2*)&gp[256 + o0];
      qr0=r.x; qr1=r.y; qz0=z.x; qz1=z.y; qn0=n.x; qn1=n.y;
    }
    mv();        // ac = full-K gate sums per (family, output pair)
    hwv = 0;
    if (isA){
      if (qt == 0){
        // GRU1: h1(t+2) = gru1(x_{t+1}, h1(t+1)) -- fully in-register
        float r0 = fast_sigmoid(pr0 + ac[0]);
        float r1 = fast_sigmoid(pr1 + ac[1]);
        float z0 = fast_sigmoid(pz0 + ac[2]);
        float z1 = fast_sigmoid(pz1 + ac[3]);
        float n0 = fast_tanh(pn0 + r0*ac[4]);
        float n1 = fast_tanh(pn1 + r1*ac[5]);
        h1c0 = (1.f - z0)*n0 + z0*h1c0;
        h1c1 = (1.f - z1)*n1 + z1*h1c1;
        hwv = pkh(h1c0, h1c1);
      }
    } else {
      // family combine: r,z summed; n kept separate (n = tanh(Cn + r*Dn))
      ac[0] += __shfl_xor(ac[0], 4);
      ac[1] += __shfl_xor(ac[1], 4);
      ac[2] += __shfl_xor(ac[2], 4);
      ac[3] += __shfl_xor(ac[3], 4);
      float dn0 = __shfl_xor(ac[4], 4);
      float dn1 = __shfl_xor(ac[5], 4);
      if (leadG){
        float r0 = fast_sigmoid(ac[0]);
        float r1 = fast_sigmoid(ac[1]);
        float z0 = fast_sigmoid(ac[2]);
        float z1 = fast_sigmoid(ac[3]);
        float n0 = fast_tanh(ac[4] + r0*dn0);
        float n1 = fast_tanh(ac[5] + r1*dn1);
        float g0 = (1.f - z0)*n0 + z0*h2c0;
        float g1 = (1.f - z1)*n1 + z1*h2c1;
        *(float2*)&G2[(t*32 + b)*128 + o0] = make_float2(g0, g1);
        if (t > 0){ h2c0 = g0; h2c1 = g1; }      // carry frozen at t==0
        hwv = pkh(h2c0, h2c1);
      }
    }
    BARX();                                       // all hhx reads of step t done
    if (leadA)      *(u32*)&hhx[o0 >> 6][o0 & 63]       = hwv;
    else if (leadG) *(u32*)&hhx[2 + (o0 >> 6)][o0 & 63] = hwv;
    pr0=qr0; pr1=qr1; pz0=qz0; pz1=qz1; pn0=qn0; pn1=qn1;
    BARX();                                       // new h visible
  }
}

// ---------------------------------------------------------------- K5: Kp·w_k for all G2 rows (coalesced QWt)
__launch_bounds__(128, 4)
__global__ void k_kp(const float* __restrict__ G2,
                     const float* __restrict__ QWt, const float* __restrict__ QB,
                     const float* __restrict__ MW,
                     float* __restrict__ KPWG)
{
  __shared__ __align__(16) float X[8][128];
  __shared__ float red[8][2];
  const int tid = threadIdx.x;           // c in [0,128)
  const int base = blockIdx.x * 8;       // 796 blocks x 8 rows = 6368
  for (int o = tid; o < 1024; o += 128){
    int r = o >> 7, c = o & 127;
    X[r][c] = G2[(base + r)*128 + c];
  }
  __syncthreads();
  float acc[8];
  float bias = QB[tid];
  #pragma unroll
  for (int r = 0; r < 8; r++) acc[r] = bias;
  const float4* wp = (const float4*)QWt;   // 32 groups x 128
  #pragma unroll 4
  for (int g = 0; g < 32; g++){
    float4 wv = wp[g*128 + tid];           // coalesced
    int kk = 4*g;
    #pragma unroll
    for (int r = 0; r < 8; r++){
      float4 t4 = *(const float4*)(&X[r][kk]);
      acc[r] = fmaf(t4.x, wv.x, acc[r]);
      acc[r] = fmaf(t4.y, wv.y, acc[r]);
      acc[r] = fmaf(t4.z, wv.z, acc[r]);
      acc[r] = fmaf(t4.w, wv.w, acc[r]);
    }
  }
  const float wk = MW[128 + tid];
  const int lane = tid & 63, wv_ = tid >> 6;
  #pragma unroll
  for (int r = 0; r < 8; r++){
    float pv = fast_tanh(acc[r]) * wk;
    for (int off = 32; off; off >>= 1) pv += __shfl_down(pv, off);
    if (lane == 0) red[r][wv_] = pv;
  }
  __syncthreads();
  if (tid < 8) KPWG[base + tid] = red[tid][0] + red[tid][1];
}

// ---------------------------------------------------------------- K6: predict + output
__global__ void k_pred(const int* __restrict__ question,
                       const int* __restrict__ qci, const void* __restrict__ qcm,
                       const int* __restrict__ flags,
                       const float* __restrict__ EQ, const float* __restrict__ EC,
                       const float* __restrict__ QB, const float* __restrict__ MW,
                       const float* __restrict__ G2,
                       const int* __restrict__ IDX,
                       const float* __restrict__ KPWG,
                       void* __restrict__ outp)
{
  const int blk = blockIdx.x;
  const int t = blk >> 5, b = blk & 31;
  const int tid = threadIdx.x;               // 64
  __shared__ float hist[11][132];
  __shared__ float qcs[128];
  __shared__ float og[11];
  __shared__ float kpw[11];
  __shared__ int   idxs[10];
  __shared__ float kpw0s;
  const int qid = question[b*S_ + t + 1];
  const int bflag = flags[1];
  if (tid < 10) idxs[tid] = IDX[blk*10 + tid];
  __syncthreads();
  for (int o = tid; o < 11*128; o += 64){
    int k = o >> 7, c = o & 127;
    float v;
    if (k == 0) v = G2[blk*128 + c];
    else { int s = idxs[k-1]; v = (s == 0) ? 0.f : G2[(s*32 + b)*128 + c]; }
    hist[k][c] = v;
  }
  #pragma unroll
  for (int o = tid; o < 128; o += 64){
    float v = EQ[qid*128 + o];
    #pragma unroll
    for (int q = 0; q < 4; q++){
      if (readBool(qcm, qid*4 + q, bflag))
        v += EC[qci[qid*4 + q]*128 + o];
    }
    qcs[o] = v;
  }
  {
    float pv = fast_tanh(QB[tid])      * MW[128 + tid]
             + fast_tanh(QB[tid + 64]) * MW[128 + tid + 64];
    for (int off = 32; off; off >>= 1) pv += __shfl_down(pv, off);
    if (tid == 0) kpw0s = pv;
  }
  __syncthreads();
  if (tid < 11){
    float acc = 0.f;
    for (int c = 0; c < 128; c++) acc = fmaf(qcs[c], hist[tid][c], acc);
    og[tid] = acc;
    float v;
    if (tid == 0) v = KPWG[blk];
    else { int s = idxs[tid-1]; v = (s == 0) ? kpw0s : KPWG[s*32 + b]; }
    kpw[tid] = v;
  }
  __syncthreads();
  if (tid == 0){
    float tv[11];
    #pragma unroll
    for (int k = 0; k < 11; k++){
      int valid = (k == 0) || (idxs[k-1] < t);
      tv[k] = valid ? kpw[k] : NEGV;
    }
    float m = tv[0];
    #pragma unroll
    for (int k = 1; k < 11; k++) m = fmaxf(m, tv[k]);
    float den = 0.f, num = 0.f;
    #pragma unroll
    for (int k = 0; k < 11; k++){
      float e = __expf(tv[k] - m);
      den += e;
      num = fmaf(e, og[k], num);
    }
    float p = num / den;
    int col = (t == 0) ? 0 : (t + 1);
    if (flags[0]){
      ((float*)outp)[b*S_ + col] = p;
      if (t == 0) ((float*)outp)[b*S_ + 1] = 0.f;
    } else {
      ((u16*)outp)[b*S_ + col] = f2bf(p);
      if (t == 0) ((u16*)outp)[b*S_ + 1] = (u16)0;
    }
  }
}

// ---------------------------------------------------------------- launcher
extern "C" void kernel_launch(void* const* d_in, const int* in_sizes, int n_in,
                              void* d_out, int out_size, void* d_ws, size_t ws_size,
                              hipStream_t stream)
{
  (void)in_sizes; (void)n_in; (void)out_size; (void)ws_size;
  const int* question      = (const int*)d_in[0];
  const int* response      = (const int*)d_in[1];
  const void* maskp        = d_in[2];
  const int* q_neighbors   = (const int*)d_in[3];
  const int* s_neighbors   = (const int*)d_in[4];
  const int* q_concept_idx = (const int*)d_in[5];
  const void* q_concept_mask = d_in[6];

  static const int CN[NCVT] = {2560000,256000,256,98304,49152,384,384,49152,49152,
                               384,384,49152,384,16384,128,16384,128,16384,128,
                               256,1,4096,4096};
  CvtArgs ca;
  int off = 0;
  for (int i = 0; i < NCVT; i++){
    ca.s[i] = d_in[7 + i];
    ca.nreal[i] = CN[i];
    ca.off[i] = off;
    off += (CN[i] + 3) & ~3;
  }
  ca.off[NCVT] = off;
  const int total = off;

  char* ws = (char*)d_ws;
  size_t wo = 0;
  auto alloc = [&](size_t bytes) -> void* {
    void* p = ws + wo;
    wo = (wo + bytes + 255) & ~(size_t)255;
    return p;
  };
  int*   flags = (int*)  alloc(16);
  float* CVT   = (float*)alloc((size_t)total * 4);
  float* EQREC = (float*)alloc((size_t)B_*S_*D_*4);
  float* GI1   = (float*)alloc((size_t)T_*B_*384*4);
  float* G2    = (float*)alloc((size_t)T_*B_*D_*4);
  int*   IDX   = (int*)  alloc((size_t)T_*B_*10*4);
  float* KPWG  = (float*)alloc((size_t)T_*B_*4);
  u32*   W3    = (u32*)  alloc(73728*4);
  u32*   AWt   = (u32*)  alloc(24576*4);
  u32*   ALWt  = (u32*)  alloc(8192*4);
  u32*   WIH1t = (u32*)  alloc(49152*4);
  float* QWt   = (float*)alloc(16384*4);

  const float* EQ   = CVT + ca.off[0];
  const float* EC   = CVT + ca.off[1];
  const float* ECOR = CVT + ca.off[2];
  const float* WIH1 = CVT + ca.off[3];
  const float* WHH1 = CVT + ca.off[4];
  const float* BIH1 = CVT + ca.off[5];
  const float* BHH1 = CVT + ca.off[6];
  const float* WIH2 = CVT + ca.off[7];
  const float* WHH2 = CVT + ca.off[8];
  const float* BIH2 = CVT + ca.off[9];
  const float* BHH2 = CVT + ca.off[10];
  const float* AW   = CVT + ca.off[11];
  const float* AB   = CVT + ca.off[12];
  const float* ALW  = CVT + ca.off[13];
  const float* ALB  = CVT + ca.off[14];
  const float* QW   = CVT + ca.off[15];
  const float* QB   = CVT + ca.off[16];
  const float* MW   = CVT + ca.off[19];
  const float* H1I  = CVT + ca.off[21];
  const float* H2I  = CVT + ca.off[22];

  k_sniff2<<<1, 256, 0, stream>>>((const u16*)d_in[7], (const unsigned char*)maskp, flags);
  k_cvt<<<(total + 255)/256, 256, 0, stream>>>(ca, flags, CVT);
  k_prep<<<192, 256, 0, stream>>>(WHH1, WHH2, AW, ALW, WIH1, WIH2, QW,
                                  W3, AWt, ALWt, WIH1t, QWt);
  k_agg<<<B_*S_/2, 256, 0, stream>>>(question, q_neighbors, s_neighbors, EQ, EC,
                                     AWt, AB, ALWt, ALB, maskp, flags, EQREC);
  k_gi1<<<dim3(T_, 4), 384, 0, stream>>>(EQREC, response, ECOR, WIH1t, BIH1, GI1);
  k_topk<<<T_*B_, 64, 0, stream>>>(question, EQ, IDX);
  k_chain12<<<B_, 768, 0, stream>>>(GI1, (const uint4*)W3, BHH1, BIH2, BHH2,
                                    H1I, H2I, G2);
  k_kp<<<T_*B_/8, 128, 0, stream>>>(G2, QWt, QB, MW, KPWG);
  k_pred<<<T_*B_, 64, 0, stream>>>(question, q_concept_idx, q_concept_mask, flags,
                                   EQ, EC, QB, MW, G2, IDX, KPWG, d_out);
}

// Round 7
// 531.794 us; speedup vs baseline: 1.3575x; 1.3575x over previous
//
#include <hip/hip_runtime.h>
#include <math.h>

typedef unsigned short u16;
typedef unsigned int   u32;
typedef __attribute__((ext_vector_type(2))) _Float16 half2_t;

#define B_   32
#define S_   200
#define D_   128
#define T_   199
#define NEGV (-1e30f)

__device__ __forceinline__ float bf2f(u16 u){
  union { u32 i; float f; } v; v.i = ((u32)u) << 16; return v.f;
}
__device__ __forceinline__ u16 f2bf(float f){
  union { float f; u32 i; } v; v.f = f;
  u32 x = v.i;
  return (u16)((x + 0x7fffu + ((x >> 16) & 1u)) >> 16);   // RNE
}
__device__ __forceinline__ u16 f2h(float x){
  union { _Float16 h; u16 u; } v; v.h = (_Float16)x; return v.u;
}
__device__ __forceinline__ float h2f(u16 u){
  union { u16 u; _Float16 h; } v; v.u = u; return (float)v.h;
}
__device__ __forceinline__ u32 pkh(float lo, float hi){
  return ((u32)f2h(hi) << 16) | f2h(lo);
}
// 2 MACs/instr: f32 += f16x2 . f16x2  (v_dot2_f32_f16)
__device__ __forceinline__ float dot2f(u32 w, u32 h, float acc){
#if __has_builtin(__builtin_amdgcn_fdot2)
  union { u32 u; half2_t h2; } a, b;
  a.u = w; b.u = h;
  return __builtin_amdgcn_fdot2(a.h2, b.h2, acc, false);
#else
  union { u32 u; _Float16 f[2]; } a, b;
  a.u = w; b.u = h;
  acc = fmaf((float)a.f[0], (float)b.f[0], acc);
  return fmaf((float)a.f[1], (float)b.f[1], acc);
#endif
}
__device__ __forceinline__ float fast_sigmoid(float x){ return 1.f/(1.f+__expf(-x)); }
__device__ __forceinline__ float fast_tanh(float x){
  float e = __expf(2.f*x);
  return 1.f - 2.f/(e + 1.f);
}

// Raw barrier: drains LDS ops only, NOT vmcnt. __syncthreads would force
// s_waitcnt vmcnt(0) and kill the cross-step global prefetch / store overlap.
#define BARX() asm volatile("s_waitcnt lgkmcnt(0)\n\ts_barrier" ::: "memory")

// Keep a loaded value opaque (no rematerialization across the asm).
#define PINV(x) asm volatile("" : "+v"(x))

// bool storage modes: 0=int32, 1=u8, 2=bf16, 3=f32
__device__ __forceinline__ int readBool(const void* p, int i, int m){
  if (m == 0) return ((const int*)p)[i] != 0;
  if (m == 1) return ((const unsigned char*)p)[i] != 0;
  if (m == 2) return ((const u16*)p)[i] != 0;
  return ((const u32*)p)[i] != 0;
}

__device__ __forceinline__ float dot128f(const float* __restrict__ w,
                                         const float* __restrict__ x){
  float acc = 0.f;
  const float4* wp = (const float4*)w;
  #pragma unroll 8
  for (int i = 0; i < 32; i++){
    float4 v = wp[i]; int k = 4*i;
    acc = fmaf(v.x, x[k],   acc);
    acc = fmaf(v.y, x[k+1], acc);
    acc = fmaf(v.z, x[k+2], acc);
    acc = fmaf(v.w, x[k+3], acc);
  }
  return acc;
}

// ---------------------------------------------------------------- sniffer
__global__ void k_sniff2(const u16* __restrict__ embq_raw,
                         const unsigned char* __restrict__ mask_raw,
                         int* __restrict__ flags){
  __shared__ int bad, gt1, m4, b0;
  const int tid = threadIdx.x;
  if (tid == 0){ bad = 0; gt1 = 0; m4 = 0; b0 = 0; }
  __syncthreads();
  for (int i = tid; i < 512; i += 256){
    u16 u = embq_raw[i];
    if (u){ int e = (u >> 7) & 0xFF; if (e < 0x58 || e > 0x7F) atomicAdd(&bad, 1); }
  }
  for (int i = tid; i < 1024; i += 256){
    unsigned char c = mask_raw[i];
    if (c > 1) atomicAdd(&gt1, 1);
    if (c && (i & 3)) atomicAdd(&m4, 1);
    if (c && !(i & 3)) atomicAdd(&b0, 1);
  }
  __syncthreads();
  if (tid == 0){
    flags[0] = (bad >= 16) ? 1 : 0;
    flags[1] = gt1 ? (b0 ? 2 : 3) : (m4 ? 1 : 0);
  }
}

// ---------------------------------------------------------------- convert floats -> f32
#define NCVT 23
struct CvtArgs { const void* s[NCVT]; int off[NCVT+1]; int nreal[NCVT]; };

__global__ void k_cvt(CvtArgs a, const int* __restrict__ flags, float* __restrict__ dst){
  __shared__ int f;
  if (threadIdx.x == 0) f = flags[0];
  __syncthreads();
  int gid = blockIdx.x * 256 + threadIdx.x;
  if (gid >= a.off[NCVT]) return;
  int ai = 0;
  for (int i = 1; i < NCVT; i++) if (gid >= a.off[i]) ai = i;
  int i = gid - a.off[ai];
  float v = 0.f;
  if (i < a.nreal[ai])
    v = f ? ((const float*)a.s[ai])[i] : bf2f(((const u16*)a.s[ai])[i]);
  dst[gid] = v;
}

// ---------------------------------------------------------------- prep
__global__ void k_prep(const float* __restrict__ WHH1, const float* __restrict__ WHH2,
                       const float* __restrict__ AW,   const float* __restrict__ ALW,
                       const float* __restrict__ WIH1, const float* __restrict__ WIH2,
                       const float* __restrict__ QW,
                       u16* __restrict__ WHH1h, u16* __restrict__ WHH2h,
                       u16* __restrict__ WIH2h,
                       u32* __restrict__ AWt,   u32* __restrict__ ALWt,
                       u32* __restrict__ WIH1t, float* __restrict__ QWt)
{
  const int gid0 = blockIdx.x*256 + threadIdx.x;
  const int stride = gridDim.x*256;
  for (int g = gid0; g < 49152; g += stride){
    WHH1h[g] = f2h(WHH1[g]);
    WHH2h[g] = f2h(WHH2[g]);
    WIH2h[g] = f2h(WIH2[g]);
  }
  // AW: 3 stages of 128x128 -> 8192 u32/stage
  for (int g = gid0; g < 24576; g += stride){
    int s = g >> 13, w = g & 8191;
    int k8 = w >> 9, r = w & 511, c = r >> 2, j = r & 3;
    const float* b = AW + s*16384 + c*128 + k8*8 + 2*j;
    AWt[g] = pkh(b[0], b[1]);
  }
  // ALW: 128x128
  for (int g = gid0; g < 8192; g += stride){
    int k8 = g >> 9, r = g & 511, c = r >> 2, j = r & 3;
    const float* b = ALW + c*128 + k8*8 + 2*j;
    ALWt[g] = pkh(b[0], b[1]);
  }
  // WIH1: 384x256 -> 32 groups x 1536
  for (int g = gid0; g < 49152; g += stride){
    int k8 = g / 1536, r = g % 1536, c = r >> 2, j = r & 3;
    const float* b = WIH1 + c*256 + k8*8 + 2*j;
    WIH1t[g] = pkh(b[0], b[1]);
  }
  // QW: 128x128 f32 -> float4 column layout (32 groups of 4 k)
  for (int g = gid0; g < 16384; g += stride){
    int k4 = g >> 9, r = g & 511, c = r >> 2, j = r & 3;
    QWt[g] = QW[c*128 + k4*4 + j];
  }
}

// ---------------------------------------------------------------- K1: hop aggregation (f16 dot2, coalesced Wt)
template<int ROWS>
__device__ __forceinline__ void agg_stage_h(const u16* __restrict__ tmph,
    const u32* __restrict__ Wt, const float* __restrict__ bg,
    u16* __restrict__ outh, int c)
{
  float bias = bg[c];
  float acc[ROWS];
  #pragma unroll
  for (int r = 0; r < ROWS; r++) acc[r] = bias;
  const uint4* wp = (const uint4*)Wt;
  if constexpr (ROWS <= 4){
    float acc2[ROWS];
    #pragma unroll
    for (int r = 0; r < ROWS; r++) acc2[r] = 0.f;
    #pragma unroll 4
    for (int g = 0; g < 16; g++){
      uint4 wv = wp[g*128 + c];          // coalesced: lanes consecutive
      #pragma unroll
      for (int r = 0; r < ROWS; r++){
        uint4 hv = *(const uint4*)(tmph + r*128 + g*8);   // LDS broadcast
        acc[r]  = dot2f(wv.x, hv.x, acc[r]);
        acc2[r] = dot2f(wv.y, hv.y, acc2[r]);
        acc[r]  = dot2f(wv.z, hv.z, acc[r]);
        acc2[r] = dot2f(wv.w, hv.w, acc2[r]);
      }
    }
    #pragma unroll
    for (int r = 0; r < ROWS; r++)
      outh[r*128 + c] = f2h(fast_tanh(acc[r] + acc2[r]));
  } else {
    #pragma unroll 4
    for (int g = 0; g < 16; g++){
      uint4 wv = wp[g*128 + c];
      #pragma unroll
      for (int r = 0; r < ROWS; r++){
        uint4 hv = *(const uint4*)(tmph + r*128 + g*8);
        acc[r] = dot2f(wv.x, hv.x, acc[r]);
        acc[r] = dot2f(wv.y, hv.y, acc[r]);
        acc[r] = dot2f(wv.z, hv.z, acc[r]);
        acc[r] = dot2f(wv.w, hv.w, acc[r]);
      }
    }
    #pragma unroll
    for (int r = 0; r < ROWS; r++)
      outh[r*128 + c] = f2h(fast_tanh(acc[r]));
  }
}

__launch_bounds__(256, 4)
__global__ void k_agg(const int* __restrict__ question,
                      const int* __restrict__ q_neighbors,
                      const int* __restrict__ s_neighbors,
                      const float* __restrict__ EQ,
                      const float* __restrict__ EC,
                      const u32* __restrict__ AWt,
                      const float* __restrict__ AB,
                      const u32* __restrict__ ALWt,
                      const float* __restrict__ ALB,
                      const void* __restrict__ maskp,
                      const int* __restrict__ flags,
                      float* __restrict__ EQREC)
{
  __shared__ __align__(16) u16 e0h[2][128];
  __shared__ __align__(16) u16 e1h[2][512];
  __shared__ __align__(16) u16 e2h[2][2048];
  __shared__ __align__(16) u16 tmph[2][2048];
  __shared__ int nn1[2][4]; __shared__ int nn2[2][16]; __shared__ int nn3[2][64];
  __shared__ int mskS[2];
  const int tid  = threadIdx.x;
  const int c    = tid & 127;
  const int half = tid >> 7;
  const int bs   = blockIdx.x*2 + half;
  const int n0   = question[bs];
  u16* tp = tmph[half];

  // EQREC[bs] = mask ? agg : EQ[n0]; if BOTH halves are unmasked, the whole
  // aggregation pipeline is dead -> write passthrough and exit (25% of blocks;
  // block-uniform branch, taken before any further barrier).
  if (c == 0) mskS[half] = readBool(maskp, bs, flags[1]);
  __syncthreads();
  const int msk = mskS[half];
  if ((mskS[0] | mskS[1]) == 0){
    EQREC[bs*128 + c] = EQ[n0*128 + c];
    return;
  }

  if (c < 4) nn1[half][c] = q_neighbors[n0*4 + c];
  __syncthreads();
  if (c < 16) nn2[half][c] = s_neighbors[nn1[half][c>>2]*4 + (c&3)];
  __syncthreads();
  if (c < 64) nn3[half][c] = q_neighbors[nn2[half][c>>2]*4 + (c&3)];
  e0h[half][c] = f2h(EQ[n0*128 + c]);
  #pragma unroll
  for (int r = 0; r < 4; r++)  e1h[half][r*128 + c] = f2h(EC[nn1[half][r]*128 + c]);
  #pragma unroll 4
  for (int r = 0; r < 16; r++) e2h[half][r*128 + c] = f2h(EQ[nn2[half][r]*128 + c]);
  __syncthreads();

  auto fill_e0 = [&](){
    float v = 0.25f*(h2f(e1h[half][c]) + h2f(e1h[half][128+c])
                   + h2f(e1h[half][256+c]) + h2f(e1h[half][384+c]))
            + h2f(e0h[half][c]);
    tp[c] = f2h(v);
  };
  auto fill_e1 = [&](){
    #pragma unroll
    for (int r = 0; r < 4; r++){
      float v = 0.25f*(h2f(e2h[half][(4*r)*128+c])   + h2f(e2h[half][(4*r+1)*128+c])
                     + h2f(e2h[half][(4*r+2)*128+c]) + h2f(e2h[half][(4*r+3)*128+c]))
              + h2f(e1h[half][r*128 + c]);
      tp[r*128 + c] = f2h(v);
    }
  };

  // i=0: j=0,1,2
  fill_e0(); __syncthreads();
  agg_stage_h<1>(tp, AWt, AB, e0h[half], c); __syncthreads();
  fill_e1(); __syncthreads();
  agg_stage_h<4>(tp, AWt + 8192, AB + 128, e1h[half], c); __syncthreads();
  #pragma unroll 2
  for (int r = 0; r < 16; r++){
    float m = 0.25f*( EC[nn3[half][4*r]*128+c]   + EC[nn3[half][4*r+1]*128+c]
                    + EC[nn3[half][4*r+2]*128+c] + EC[nn3[half][4*r+3]*128+c] );
    tp[r*128 + c] = f2h(m + h2f(e2h[half][r*128 + c]));
  }
  __syncthreads();
  agg_stage_h<16>(tp, AWt + 16384, AB + 256, e2h[half], c); __syncthreads();
  // i=1: j=0,1
  fill_e0(); __syncthreads();
  agg_stage_h<1>(tp, AWt, AB, e0h[half], c); __syncthreads();
  fill_e1(); __syncthreads();
  agg_stage_h<4>(tp, AWt + 8192, AB + 128, e1h[half], c); __syncthreads();
  // i=2: j=0
  fill_e0(); __syncthreads();
  agg_stage_h<1>(tp, AWt, AB, e0h[half], c); __syncthreads();
  // agg = tanh(e0 @ ALW.T + ALB)
  agg_stage_h<1>(e0h[half], ALWt, ALB, tp, c); __syncthreads();
  EQREC[bs*128 + c] = msk ? h2f(tp[c]) : EQ[n0*128 + c];
}

// ---------------------------------------------------------------- K2: gi1 precompute (K=256, f16 dot2, coalesced)
__launch_bounds__(384, 1)
__global__ void k_gi1(const float* __restrict__ EQREC,
                      const int* __restrict__ response,
                      const float* __restrict__ ECOR,
                      const u32* __restrict__ WIH1t,
                      const float* __restrict__ BIH1,
                      float* __restrict__ GI1)
{
  const int t  = blockIdx.x;
  const int bg = blockIdx.y;
  const int tid = threadIdx.x;
  __shared__ __align__(16) u16 X[8][256];
  for (int o = tid; o < 2048; o += 384){
    int bb = o >> 8, k = o & 255;
    int b = bg*8 + bb;
    float v = (k < 128) ? EQREC[(b*S_ + t)*128 + k]
                        : ECOR[response[b*S_ + t]*128 + (k - 128)];
    X[bb][k] = f2h(v);
  }
  __syncthreads();
  float bias = BIH1[tid];
  float acc[8];
  #pragma unroll
  for (int i = 0; i < 8; i++) acc[i] = bias;
  const uint4* wp = (const uint4*)WIH1t;   // 32 groups x 384
  #pragma unroll 4
  for (int g = 0; g < 32; g++){
    uint4 wv = wp[g*384 + tid];            // coalesced
    #pragma unroll
    for (int bb = 0; bb < 8; bb++){
      uint4 hv = *(const uint4*)(&X[bb][g*8]);   // broadcast
      acc[bb] = dot2f(wv.x, hv.x, acc[bb]);
      acc[bb] = dot2f(wv.y, hv.y, acc[bb]);
      acc[bb] = dot2f(wv.z, hv.z, acc[bb]);
      acc[bb] = dot2f(wv.w, hv.w, acc[bb]);
    }
  }
  #pragma unroll
  for (int bb = 0; bb < 8; bb++)
    GI1[(t*32 + bg*8 + bb)*384 + tid] = acc[bb];
}

// ---------------------------------------------------------------- K3: scores + top-10
__global__ void k_topk(const int* __restrict__ question,
                       const float* __restrict__ EQ,
                       int* __restrict__ IDX)
{
  const int blk = blockIdx.x;
  const int t = blk >> 5, b = blk & 31;
  const int tid = threadIdx.x;               // 64
  __shared__ __align__(16) float qn[128];
  const int qid = question[b*S_ + t + 1];
  for (int o = tid; o < 128; o += 64) qn[o] = EQ[qid*128 + o];
  __syncthreads();
  float val[4]; int sv[4];
  #pragma unroll
  for (int i = 0; i < 4; i++){
    int s = tid + 64*i;
    sv[i] = s;
    float v = -3.0e38f;
    if (s < S_) v = (s < t) ? dot128f(EQ + question[b*S_ + s]*128, qn) : NEGV;
    val[i] = v;
  }
  for (int r = 0; r < 10; r++){
    float bv = -3.0e38f; int bi = 0x3fffffff;
    #pragma unroll
    for (int i = 0; i < 4; i++){
      if (val[i] > bv || (val[i] == bv && sv[i] < bi)){ bv = val[i]; bi = sv[i]; }
    }
    for (int off = 32; off; off >>= 1){
      float ov = __shfl_down(bv, off);
      int   oi = __shfl_down(bi, off);
      if (ov > bv || (ov == bv && oi < bi)){ bv = ov; bi = oi; }
    }
    int win = __shfl(bi, 0);
    if (tid == 0) IDX[blk*10 + r] = win;
    #pragma unroll
    for (int i = 0; i < 4; i++) if (sv[i] == win) val[i] = -3.0e38f;
  }
}

// ---------------------------------------------------------------- K4: FUSED h1/h2 recurrence, rows grouped by h-source
// (round-5 version, proven 203us; round-6's DPP/quarter-K variant regressed
// to 383us -- PINV'd weights spilled to scratch, VALU doubled.)
// 768 threads = 12 waves. Regroup rows so each thread's 3 rows consume the
// SAME h-vector-half => 8 uniform b128 reads/thread/step, 96 wave-reads
// total, each feeding 12 dot2. Matvec body identical for all threads.
// All role/half splits fall on wave boundaries -- no divergent barriers.
// Update phase parallelized: tid<128 GRU2/g2-store; tid in [128,256) GRU1 +
// gi1 prefetch. 2 raw barriers/step; vmcnt never drained in-loop.
__launch_bounds__(768, 3)
__global__ void k_chain12(const float* __restrict__ GI1,
                          const u16* __restrict__ WHH1h, const float* __restrict__ BHH1,
                          const u16* __restrict__ WIH2h, const float* __restrict__ BIH2,
                          const u16* __restrict__ WHH2h, const float* __restrict__ BHH2,
                          const float* __restrict__ H1I, const float* __restrict__ H2I,
                          float* __restrict__ G2)
{
  const int b   = blockIdx.x;
  const int tid = threadIdx.x;
  __shared__ __align__(16) u16 hh1[128];
  __shared__ __align__(16) u16 hh2[128];
  __shared__ __align__(16) float psBuf[2304];

  int half, r0, sidx;
  const u16* wrow;
  const u16* hbase;
  float bias0, bias1, bias2;
  if (tid < 512){
    int i = tid;
    half = (i >= 256) ? 1 : 0; i -= half*256;      // wave-uniform
    r0 = 3*i;                                      // rows r0..r0+2 in [0,768)
    wrow  = ((r0 < 384) ? (WHH1h + r0*128) : (WIH2h + (r0-384)*128)) + half*64;
    hbase = hh1 + half*64;
    sidx  = half*768 + r0;
    if (half == 0){
      if (r0 < 384){ bias0 = BHH1[r0];     bias1 = BHH1[r0+1];   bias2 = BHH1[r0+2]; }
      else         { bias0 = BIH2[r0-384]; bias1 = BIH2[r0-383]; bias2 = BIH2[r0-382]; }
    } else { bias0 = bias1 = bias2 = 0.f; }
  } else {
    int j = tid - 512;
    half = (j >= 128) ? 1 : 0; j -= half*128;      // wave-uniform
    r0 = 3*j;                                      // rows in [0,384)
    wrow  = WHH2h + r0*128 + half*64;
    hbase = hh2 + half*64;
    sidx  = 1536 + half*384 + r0;
    if (half == 0){ bias0 = BHH2[r0]; bias1 = BHH2[r0+1]; bias2 = BHH2[r0+2]; }
    else { bias0 = bias1 = bias2 = 0.f; }
  }
  uint4 Wa[8], Wb[8], Wc[8];
  {
    const uint4* p0 = (const uint4*)(wrow);
    const uint4* p1 = (const uint4*)(wrow + 128);
    const uint4* p2 = (const uint4*)(wrow + 256);
    #pragma unroll
    for (int g = 0; g < 8; g++){ Wa[g] = p0[g]; Wb[g] = p1[g]; Wc[g] = p2[g]; }
  }
  #pragma unroll
  for (int g = 0; g < 8; g++){
    PINV(Wa[g].x); PINV(Wa[g].y); PINV(Wa[g].z); PINV(Wa[g].w);
    PINV(Wb[g].x); PINV(Wb[g].y); PINV(Wb[g].z); PINV(Wb[g].w);
    PINV(Wc[g].x); PINV(Wc[g].y); PINV(Wc[g].z); PINV(Wc[g].w);
  }

  auto mv = [&](){
    float a0 = bias0, a1 = bias1, a2 = bias2;
    #pragma unroll
    for (int g = 0; g < 8; g++){
      uint4 hv = *(const uint4*)(hbase + g*8);    // uniform b128 (broadcast)
      a0 = dot2f(Wa[g].x, hv.x, a0); a0 = dot2f(Wa[g].y, hv.y, a0);
      a0 = dot2f(Wa[g].z, hv.z, a0); a0 = dot2f(Wa[g].w, hv.w, a0);
      a1 = dot2f(Wb[g].x, hv.x, a1); a1 = dot2f(Wb[g].y, hv.y, a1);
      a1 = dot2f(Wb[g].z, hv.z, a1); a1 = dot2f(Wb[g].w, hv.w, a1);
      a2 = dot2f(Wc[g].x, hv.x, a2); a2 = dot2f(Wc[g].y, hv.y, a2);
      a2 = dot2f(Wc[g].z, hv.z, a2); a2 = dot2f(Wc[g].w, hv.w, a2);
    }
    psBuf[sidx] = a0; psBuf[sidx+1] = a1; psBuf[sidx+2] = a2;
  };

  float h1c = 0.f, h2c = 0.f;
  float pc0 = 0.f, pc1 = 0.f, pc2 = 0.f;   // gi1 regs, live in tid [128,256)
  if (tid < 128){
    h2c = H2I[b*128 + tid]; hh2[tid] = f2h(h2c);
  } else if (tid < 256){
    int u = tid - 128;
    h1c = H1I[b*128 + u]; hh1[u] = f2h(h1c);
    const float* gp = GI1 + b*384;         // gi1(0)
    pc0 = gp[u]; pc1 = gp[128+u]; pc2 = gp[256+u];
  }
  BARX();

  // prologue: h1(1) = gru1(x0, h1(0)); C/D partials written here are junk
  // and are overwritten before first read.
  mv();
  BARX();
  if (tid >= 128 && tid < 256){
    int u = tid - 128;
    float r = fast_sigmoid(pc0 + psBuf[u]     + psBuf[768+u]);
    float z = fast_sigmoid(pc1 + psBuf[128+u] + psBuf[896+u]);
    float n = fast_tanh(pc2 + r*(psBuf[256+u] + psBuf[1024+u]));
    h1c = (1.f - z)*n + z*h1c;
    hh1[u] = f2h(h1c);
    const float* gp = GI1 + (32 + b)*384;  // gi1(1)
    pc0 = gp[u]; pc1 = gp[128+u]; pc2 = gp[256+u];
  }
  BARX();

  float* gout = G2 + b*128 + tid;          // dereferenced only for tid<128
  #pragma unroll 1
  for (int t = 0; t < T_; t++){
    // prefetch gi1(t+2) (consumed next iteration; hidden under matvec)
    float pn0 = 0.f, pn1 = 0.f, pn2 = 0.f;
    if (tid >= 128 && tid < 256){
      int u = tid - 128;
      int tp = (t + 2 < T_) ? t + 2 : T_ - 1;
      const float* gp = GI1 + (tp*32 + b)*384;
      pn0 = gp[u]; pn1 = gp[128+u]; pn2 = gp[256+u];
    }
    mv();   // a = WHH1@h1(t+1), c = WIH2@h1(t+1), d = WHH2@h2carry
    BARX();
    if (tid < 128){
      // GRU2: g2(t) = gru2(h1(t+1), h2carry)
      float cs0 = psBuf[384+tid]  + psBuf[1152+tid];
      float cs1 = psBuf[512+tid]  + psBuf[1280+tid];
      float cs2 = psBuf[640+tid]  + psBuf[1408+tid];
      float ds0 = psBuf[1536+tid] + psBuf[1920+tid];
      float ds1 = psBuf[1664+tid] + psBuf[2048+tid];
      float ds2 = psBuf[1792+tid] + psBuf[2176+tid];
      float r2 = fast_sigmoid(cs0 + ds0);
      float z2 = fast_sigmoid(cs1 + ds1);
      float n2 = fast_tanh(cs2 + r2*ds2);
      float g  = (1.f - z2)*n2 + z2*h2c;
      gout[t*4096] = g;                    // G2[(t*32+b)*128+tid]
      if (t > 0) h2c = g;                  // reference: h2 carry frozen at t==0
      hh2[tid] = f2h(h2c);
    } else if (tid < 256){
      // GRU1: h1(t+2) = gru1(x_{t+1}, h1(t+1))
      int u = tid - 128;
      float as0 = psBuf[u]     + psBuf[768+u];
      float as1 = psBuf[128+u] + psBuf[896+u];
      float as2 = psBuf[256+u] + psBuf[1024+u];
      float r1 = fast_sigmoid(pc0 + as0);
      float z1 = fast_sigmoid(pc1 + as1);
      float n1 = fast_tanh(pc2 + r1*as2);
      h1c = (1.f - z1)*n1 + z1*h1c;
      hh1[u] = f2h(h1c);
    }
    pc0 = pn0; pc1 = pn1; pc2 = pn2;
    BARX();
  }
}

// ---------------------------------------------------------------- K5: Kp·w_k for all G2 rows (coalesced QWt)
__launch_bounds__(128, 4)
__global__ void k_kp(const float* __restrict__ G2,
                     const float* __restrict__ QWt, const float* __restrict__ QB,
                     const float* __restrict__ MW,
                     float* __restrict__ KPWG)
{
  __shared__ __align__(16) float X[8][128];
  __shared__ float red[8][2];
  const int tid = threadIdx.x;           // c in [0,128)
  const int base = blockIdx.x * 8;       // 796 blocks x 8 rows = 6368
  for (int o = tid; o < 1024; o += 128){
    int r = o >> 7, c = o & 127;
    X[r][c] = G2[(base + r)*128 + c];
  }
  __syncthreads();
  float acc[8];
  float bias = QB[tid];
  #pragma unroll
  for (int r = 0; r < 8; r++) acc[r] = bias;
  const float4* wp = (const float4*)QWt;   // 32 groups x 128
  #pragma unroll 4
  for (int g = 0; g < 32; g++){
    float4 wv = wp[g*128 + tid];           // coalesced
    int kk = 4*g;
    #pragma unroll
    for (int r = 0; r < 8; r++){
      float4 t4 = *(const float4*)(&X[r][kk]);
      acc[r] = fmaf(t4.x, wv.x, acc[r]);
      acc[r] = fmaf(t4.y, wv.y, acc[r]);
      acc[r] = fmaf(t4.z, wv.z, acc[r]);
      acc[r] = fmaf(t4.w, wv.w, acc[r]);
    }
  }
  const float wk = MW[128 + tid];
  const int lane = tid & 63, wv_ = tid >> 6;
  #pragma unroll
  for (int r = 0; r < 8; r++){
    float pv = fast_tanh(acc[r]) * wk;
    for (int off = 32; off; off >>= 1) pv += __shfl_down(pv, off);
    if (lane == 0) red[r][wv_] = pv;
  }
  __syncthreads();
  if (tid < 8) KPWG[base + tid] = red[tid][0] + red[tid][1];
}

// ---------------------------------------------------------------- K6: predict + output
__global__ void k_pred(const int* __restrict__ question,
                       const int* __restrict__ qci, const void* __restrict__ qcm,
                       const int* __restrict__ flags,
                       const float* __restrict__ EQ, const float* __restrict__ EC,
                       const float* __restrict__ QB, const float* __restrict__ MW,
                       const float* __restrict__ G2,
                       const int* __restrict__ IDX,
                       const float* __restrict__ KPWG,
                       void* __restrict__ outp)
{
  const int blk = blockIdx.x;
  const int t = blk >> 5, b = blk & 31;
  const int tid = threadIdx.x;               // 64
  __shared__ float hist[11][132];
  __shared__ float qcs[128];
  __shared__ float og[11];
  __shared__ float kpw[11];
  __shared__ int   idxs[10];
  __shared__ float kpw0s;
  const int qid = question[b*S_ + t + 1];
  const int bflag = flags[1];
  if (tid < 10) idxs[tid] = IDX[blk*10 + tid];
  __syncthreads();
  for (int o = tid; o < 11*128; o += 64){
    int k = o >> 7, c = o & 127;
    float v;
    if (k == 0) v = G2[blk*128 + c];
    else { int s = idxs[k-1]; v = (s == 0) ? 0.f : G2[(s*32 + b)*128 + c]; }
    hist[k][c] = v;
  }
  #pragma unroll
  for (int o = tid; o < 128; o += 64){
    float v = EQ[qid*128 + o];
    #pragma unroll
    for (int q = 0; q < 4; q++){
      if (readBool(qcm, qid*4 + q, bflag))
        v += EC[qci[qid*4 + q]*128 + o];
    }
    qcs[o] = v;
  }
  {
    float pv = fast_tanh(QB[tid])      * MW[128 + tid]
             + fast_tanh(QB[tid + 64]) * MW[128 + tid + 64];
    for (int off = 32; off; off >>= 1) pv += __shfl_down(pv, off);
    if (tid == 0) kpw0s = pv;
  }
  __syncthreads();
  if (tid < 11){
    float acc = 0.f;
    for (int c = 0; c < 128; c++) acc = fmaf(qcs[c], hist[tid][c], acc);
    og[tid] = acc;
    float v;
    if (tid == 0) v = KPWG[blk];
    else { int s = idxs[tid-1]; v = (s == 0) ? kpw0s : KPWG[s*32 + b]; }
    kpw[tid] = v;
  }
  __syncthreads();
  if (tid == 0){
    float tv[11];
    #pragma unroll
    for (int k = 0; k < 11; k++){
      int valid = (k == 0) || (idxs[k-1] < t);
      tv[k] = valid ? kpw[k] : NEGV;
    }
    float m = tv[0];
    #pragma unroll
    for (int k = 1; k < 11; k++) m = fmaxf(m, tv[k]);
    float den = 0.f, num = 0.f;
    #pragma unroll
    for (int k = 0; k < 11; k++){
      float e = __expf(tv[k] - m);
      den += e;
      num = fmaf(e, og[k], num);
    }
    float p = num / den;
    int col = (t == 0) ? 0 : (t + 1);
    if (flags[0]){
      ((float*)outp)[b*S_ + col] = p;
      if (t == 0) ((float*)outp)[b*S_ + 1] = 0.f;
    } else {
      ((u16*)outp)[b*S_ + col] = f2bf(p);
      if (t == 0) ((u16*)outp)[b*S_ + 1] = (u16)0;
    }
  }
}

// ---------------------------------------------------------------- launcher
extern "C" void kernel_launch(void* const* d_in, const int* in_sizes, int n_in,
                              void* d_out, int out_size, void* d_ws, size_t ws_size,
                              hipStream_t stream)
{
  (void)in_sizes; (void)n_in; (void)out_size; (void)ws_size;
  const int* question      = (const int*)d_in[0];
  const int* response      = (const int*)d_in[1];
  const void* maskp        = d_in[2];
  const int* q_neighbors   = (const int*)d_in[3];
  const int* s_neighbors   = (const int*)d_in[4];
  const int* q_concept_idx = (const int*)d_in[5];
  const void* q_concept_mask = d_in[6];

  static const int CN[NCVT] = {2560000,256000,256,98304,49152,384,384,49152,49152,
                               384,384,49152,384,16384,128,16384,128,16384,128,
                               256,1,4096,4096};
  CvtArgs ca;
  int off = 0;
  for (int i = 0; i < NCVT; i++){
    ca.s[i] = d_in[7 + i];
    ca.nreal[i] = CN[i];
    ca.off[i] = off;
    off += (CN[i] + 3) & ~3;
  }
  ca.off[NCVT] = off;
  const int total = off;

  char* ws = (char*)d_ws;
  size_t wo = 0;
  auto alloc = [&](size_t bytes) -> void* {
    void* p = ws + wo;
    wo = (wo + bytes + 255) & ~(size_t)255;
    return p;
  };
  int*   flags = (int*)  alloc(16);
  float* CVT   = (float*)alloc((size_t)total * 4);
  float* EQREC = (float*)alloc((size_t)B_*S_*D_*4);
  float* GI1   = (float*)alloc((size_t)T_*B_*384*4);
  float* G2    = (float*)alloc((size_t)T_*B_*D_*4);
  int*   IDX   = (int*)  alloc((size_t)T_*B_*10*4);
  float* KPWG  = (float*)alloc((size_t)T_*B_*4);
  u16*   WHH1h = (u16*)  alloc(49152*2);
  u16*   WHH2h = (u16*)  alloc(49152*2);
  u16*   WIH2h = (u16*)  alloc(49152*2);
  u32*   AWt   = (u32*)  alloc(24576*4);
  u32*   ALWt  = (u32*)  alloc(8192*4);
  u32*   WIH1t = (u32*)  alloc(49152*4);
  float* QWt   = (float*)alloc(16384*4);

  const float* EQ   = CVT + ca.off[0];
  const float* EC   = CVT + ca.off[1];
  const float* ECOR = CVT + ca.off[2];
  const float* WIH1 = CVT + ca.off[3];
  const float* WHH1 = CVT + ca.off[4];
  const float* BIH1 = CVT + ca.off[5];
  const float* BHH1 = CVT + ca.off[6];
  const float* WIH2 = CVT + ca.off[7];
  const float* WHH2 = CVT + ca.off[8];
  const float* BIH2 = CVT + ca.off[9];
  const float* BHH2 = CVT + ca.off[10];
  const float* AW   = CVT + ca.off[11];
  const float* AB   = CVT + ca.off[12];
  const float* ALW  = CVT + ca.off[13];
  const float* ALB  = CVT + ca.off[14];
  const float* QW   = CVT + ca.off[15];
  const float* QB   = CVT + ca.off[16];
  const float* MW   = CVT + ca.off[19];
  const float* H1I  = CVT + ca.off[21];
  const float* H2I  = CVT + ca.off[22];

  k_sniff2<<<1, 256, 0, stream>>>((const u16*)d_in[7], (const unsigned char*)maskp, flags);
  k_cvt<<<(total + 255)/256, 256, 0, stream>>>(ca, flags, CVT);
  k_prep<<<192, 256, 0, stream>>>(WHH1, WHH2, AW, ALW, WIH1, WIH2, QW,
                                  WHH1h, WHH2h, WIH2h, AWt, ALWt, WIH1t, QWt);
  k_agg<<<B_*S_/2, 256, 0, stream>>>(question, q_neighbors, s_neighbors, EQ, EC,
                                     AWt, AB, ALWt, ALB, maskp, flags, EQREC);
  k_gi1<<<dim3(T_, 4), 384, 0, stream>>>(EQREC, response, ECOR, WIH1t, BIH1, GI1);
  k_topk<<<T_*B_, 64, 0, stream>>>(question, EQ, IDX);
  k_chain12<<<B_, 768, 0, stream>>>(GI1, WHH1h, BHH1, WIH2h, BIH2, WHH2h, BHH2,
                                    H1I, H2I, G2);
  k_kp<<<T_*B_/8, 128, 0, stream>>>(G2, QWt, QB, MW, KPWG);
  k_pred<<<T_*B_, 64, 0, stream>>>(question, q_concept_idx, q_concept_mask, flags,
                                   EQ, EC, QB, MW, G2, IDX, KPWG, d_out);
}

// Round 9
// 473.105 us; speedup vs baseline: 1.5259x; 1.1241x over previous
//
#include <hip/hip_runtime.h>
#include <math.h>

typedef unsigned short u16;
typedef unsigned int   u32;
typedef __attribute__((ext_vector_type(2))) _Float16 half2_t;

#define B_   32
#define S_   200
#define D_   128
#define T_   199
#define NEGV (-1e30f)

__device__ __forceinline__ float bf2f(u16 u){
  union { u32 i; float f; } v; v.i = ((u32)u) << 16; return v.f;
}
__device__ __forceinline__ u16 f2bf(float f){
  union { float f; u32 i; } v; v.f = f;
  u32 x = v.i;
  return (u16)((x + 0x7fffu + ((x >> 16) & 1u)) >> 16);   // RNE
}
__device__ __forceinline__ u16 f2h(float x){
  union { _Float16 h; u16 u; } v; v.h = (_Float16)x; return v.u;
}
__device__ __forceinline__ float h2f(u16 u){
  union { u16 u; _Float16 h; } v; v.u = u; return (float)v.h;
}
__device__ __forceinline__ u32 pkh(float lo, float hi){
  return ((u32)f2h(hi) << 16) | f2h(lo);
}
// 2 MACs/instr: f32 += f16x2 . f16x2  (v_dot2_f32_f16)
__device__ __forceinline__ float dot2f(u32 w, u32 h, float acc){
#if __has_builtin(__builtin_amdgcn_fdot2)
  union { u32 u; half2_t h2; } a, b;
  a.u = w; b.u = h;
  return __builtin_amdgcn_fdot2(a.h2, b.h2, acc, false);
#else
  union { u32 u; _Float16 f[2]; } a, b;
  a.u = w; b.u = h;
  acc = fmaf((float)a.f[0], (float)b.f[0], acc);
  return fmaf((float)a.f[1], (float)b.f[1], acc);
#endif
}
__device__ __forceinline__ float fast_sigmoid(float x){ return 1.f/(1.f+__expf(-x)); }
__device__ __forceinline__ float fast_tanh(float x){
  float e = __expf(2.f*x);
  return 1.f - 2.f/(e + 1.f);
}

// Raw barrier: drains LDS ops only, NOT vmcnt. __syncthreads would force
// s_waitcnt vmcnt(0) and kill the cross-step global prefetch / store overlap.
#define BARX() asm volatile("s_waitcnt lgkmcnt(0)\n\ts_barrier" ::: "memory")

// Keep a loaded value opaque (no rematerialization across the asm).
#define PINV(x) asm volatile("" : "+v"(x))

// bool storage modes: 0=int32, 1=u8, 2=bf16, 3=f32
__device__ __forceinline__ int readBool(const void* p, int i, int m){
  if (m == 0) return ((const int*)p)[i] != 0;
  if (m == 1) return ((const unsigned char*)p)[i] != 0;
  if (m == 2) return ((const u16*)p)[i] != 0;
  return ((const u32*)p)[i] != 0;
}

__device__ __forceinline__ float dot128f(const float* __restrict__ w,
                                         const float* __restrict__ x){
  float acc = 0.f;
  const float4* wp = (const float4*)w;
  #pragma unroll 8
  for (int i = 0; i < 32; i++){
    float4 v = wp[i]; int k = 4*i;
    acc = fmaf(v.x, x[k],   acc);
    acc = fmaf(v.y, x[k+1], acc);
    acc = fmaf(v.z, x[k+2], acc);
    acc = fmaf(v.w, x[k+3], acc);
  }
  return acc;
}

// ---------------------------------------------------------------- sniffer
__global__ void k_sniff2(const u16* __restrict__ embq_raw,
                         const unsigned char* __restrict__ mask_raw,
                         int* __restrict__ flags){
  __shared__ int bad, gt1, m4, b0;
  const int tid = threadIdx.x;
  if (tid == 0){ bad = 0; gt1 = 0; m4 = 0; b0 = 0; }
  __syncthreads();
  for (int i = tid; i < 512; i += 256){
    u16 u = embq_raw[i];
    if (u){ int e = (u >> 7) & 0xFF; if (e < 0x58 || e > 0x7F) atomicAdd(&bad, 1); }
  }
  for (int i = tid; i < 1024; i += 256){
    unsigned char c = mask_raw[i];
    if (c > 1) atomicAdd(&gt1, 1);
    if (c && (i & 3)) atomicAdd(&m4, 1);
    if (c && !(i & 3)) atomicAdd(&b0, 1);
  }
  __syncthreads();
  if (tid == 0){
    flags[0] = (bad >= 16) ? 1 : 0;
    flags[1] = gt1 ? (b0 ? 2 : 3) : (m4 ? 1 : 0);
  }
}

// ---------------------------------------------------------------- convert floats -> f32
#define NCVT 23
struct CvtArgs { const void* s[NCVT]; int off[NCVT+1]; int nreal[NCVT]; };

__global__ void k_cvt(CvtArgs a, const int* __restrict__ flags, float* __restrict__ dst){
  __shared__ int f;
  if (threadIdx.x == 0) f = flags[0];
  __syncthreads();
  int gid = blockIdx.x * 256 + threadIdx.x;
  if (gid >= a.off[NCVT]) return;
  int ai = 0;
  for (int i = 1; i < NCVT; i++) if (gid >= a.off[i]) ai = i;
  int i = gid - a.off[ai];
  float v = 0.f;
  if (i < a.nreal[ai])
    v = f ? ((const float*)a.s[ai])[i] : bf2f(((const u16*)a.s[ai])[i]);
  dst[gid] = v;
}

// ---------------------------------------------------------------- prep
__global__ void k_prep(const float* __restrict__ WHH1, const float* __restrict__ WHH2,
                       const float* __restrict__ AW,   const float* __restrict__ ALW,
                       const float* __restrict__ WIH1, const float* __restrict__ WIH2,
                       const float* __restrict__ QW,
                       u16* __restrict__ WHH1h, u16* __restrict__ WHH2h,
                       u16* __restrict__ WIH2h,
                       u32* __restrict__ AWt,   u32* __restrict__ ALWt,
                       u32* __restrict__ WIH1t, float* __restrict__ QWt)
{
  const int gid0 = blockIdx.x*256 + threadIdx.x;
  const int stride = gridDim.x*256;
  for (int g = gid0; g < 49152; g += stride){
    WHH1h[g] = f2h(WHH1[g]);
    WHH2h[g] = f2h(WHH2[g]);
    WIH2h[g] = f2h(WIH2[g]);
  }
  // AW: 3 stages of 128x128 -> 8192 u32/stage
  for (int g = gid0; g < 24576; g += stride){
    int s = g >> 13, w = g & 8191;
    int k8 = w >> 9, r = w & 511, c = r >> 2, j = r & 3;
    const float* b = AW + s*16384 + c*128 + k8*8 + 2*j;
    AWt[g] = pkh(b[0], b[1]);
  }
  // ALW: 128x128
  for (int g = gid0; g < 8192; g += stride){
    int k8 = g >> 9, r = g & 511, c = r >> 2, j = r & 3;
    const float* b = ALW + c*128 + k8*8 + 2*j;
    ALWt[g] = pkh(b[0], b[1]);
  }
  // WIH1: 384x256 -> 32 groups x 1536
  for (int g = gid0; g < 49152; g += stride){
    int k8 = g / 1536, r = g % 1536, c = r >> 2, j = r & 3;
    const float* b = WIH1 + c*256 + k8*8 + 2*j;
    WIH1t[g] = pkh(b[0], b[1]);
  }
  // QW: 128x128 f32 -> float4 column layout (32 groups of 4 k)
  for (int g = gid0; g < 16384; g += stride){
    int k4 = g >> 9, r = g & 511, c = r >> 2, j = r & 3;
    QWt[g] = QW[c*128 + k4*4 + j];
  }
}

// ---------------------------------------------------------------- K1: hop aggregation (f16 dot2, coalesced Wt)
template<int ROWS>
__device__ __forceinline__ void agg_stage_h(const u16* __restrict__ tmph,
    const u32* __restrict__ Wt, const float* __restrict__ bg,
    u16* __restrict__ outh, int c)
{
  float bias = bg[c];
  float acc[ROWS];
  #pragma unroll
  for (int r = 0; r < ROWS; r++) acc[r] = bias;
  const uint4* wp = (const uint4*)Wt;
  if constexpr (ROWS <= 4){
    float acc2[ROWS];
    #pragma unroll
    for (int r = 0; r < ROWS; r++) acc2[r] = 0.f;
    #pragma unroll 4
    for (int g = 0; g < 16; g++){
      uint4 wv = wp[g*128 + c];          // coalesced: lanes consecutive
      #pragma unroll
      for (int r = 0; r < ROWS; r++){
        uint4 hv = *(const uint4*)(tmph + r*128 + g*8);   // LDS broadcast
        acc[r]  = dot2f(wv.x, hv.x, acc[r]);
        acc2[r] = dot2f(wv.y, hv.y, acc2[r]);
        acc[r]  = dot2f(wv.z, hv.z, acc[r]);
        acc2[r] = dot2f(wv.w, hv.w, acc2[r]);
      }
    }
    #pragma unroll
    for (int r = 0; r < ROWS; r++)
      outh[r*128 + c] = f2h(fast_tanh(acc[r] + acc2[r]));
  } else {
    #pragma unroll 4
    for (int g = 0; g < 16; g++){
      uint4 wv = wp[g*128 + c];
      #pragma unroll
      for (int r = 0; r < ROWS; r++){
        uint4 hv = *(const uint4*)(tmph + r*128 + g*8);
        acc[r] = dot2f(wv.x, hv.x, acc[r]);
        acc[r] = dot2f(wv.y, hv.y, acc[r]);
        acc[r] = dot2f(wv.z, hv.z, acc[r]);
        acc[r] = dot2f(wv.w, hv.w, acc[r]);
      }
    }
    #pragma unroll
    for (int r = 0; r < ROWS; r++)
      outh[r*128 + c] = f2h(fast_tanh(acc[r]));
  }
}

__launch_bounds__(256, 4)
__global__ void k_agg(const int* __restrict__ question,
                      const int* __restrict__ q_neighbors,
                      const int* __restrict__ s_neighbors,
                      const float* __restrict__ EQ,
                      const float* __restrict__ EC,
                      const u32* __restrict__ AWt,
                      const float* __restrict__ AB,
                      const u32* __restrict__ ALWt,
                      const float* __restrict__ ALB,
                      const void* __restrict__ maskp,
                      const int* __restrict__ flags,
                      float* __restrict__ EQREC)
{
  __shared__ __align__(16) u16 e0h[2][128];
  __shared__ __align__(16) u16 e1h[2][512];
  __shared__ __align__(16) u16 e2h[2][2048];
  __shared__ __align__(16) u16 tmph[2][2048];
  __shared__ int nn1[2][4]; __shared__ int nn2[2][16]; __shared__ int nn3[2][64];
  __shared__ int mskS[2];
  const int tid  = threadIdx.x;
  const int c    = tid & 127;
  const int half = tid >> 7;
  const int bs   = blockIdx.x*2 + half;
  const int n0   = question[bs];
  u16* tp = tmph[half];

  // EQREC[bs] = mask ? agg : EQ[n0]; if BOTH halves are unmasked, the whole
  // aggregation pipeline is dead -> write passthrough and exit (25% of blocks;
  // block-uniform branch, taken before any further barrier).
  if (c == 0) mskS[half] = readBool(maskp, bs, flags[1]);
  __syncthreads();
  const int msk = mskS[half];
  if ((mskS[0] | mskS[1]) == 0){
    EQREC[bs*128 + c] = EQ[n0*128 + c];
    return;
  }

  if (c < 4) nn1[half][c] = q_neighbors[n0*4 + c];
  __syncthreads();
  if (c < 16) nn2[half][c] = s_neighbors[nn1[half][c>>2]*4 + (c&3)];
  __syncthreads();
  if (c < 64) nn3[half][c] = q_neighbors[nn2[half][c>>2]*4 + (c&3)];
  e0h[half][c] = f2h(EQ[n0*128 + c]);
  #pragma unroll
  for (int r = 0; r < 4; r++)  e1h[half][r*128 + c] = f2h(EC[nn1[half][r]*128 + c]);
  #pragma unroll 4
  for (int r = 0; r < 16; r++) e2h[half][r*128 + c] = f2h(EQ[nn2[half][r]*128 + c]);
  __syncthreads();

  auto fill_e0 = [&](){
    float v = 0.25f*(h2f(e1h[half][c]) + h2f(e1h[half][128+c])
                   + h2f(e1h[half][256+c]) + h2f(e1h[half][384+c]))
            + h2f(e0h[half][c]);
    tp[c] = f2h(v);
  };
  auto fill_e1 = [&](){
    #pragma unroll
    for (int r = 0; r < 4; r++){
      float v = 0.25f*(h2f(e2h[half][(4*r)*128+c])   + h2f(e2h[half][(4*r+1)*128+c])
                     + h2f(e2h[half][(4*r+2)*128+c]) + h2f(e2h[half][(4*r+3)*128+c]))
              + h2f(e1h[half][r*128 + c]);
      tp[r*128 + c] = f2h(v);
    }
  };

  // i=0: j=0,1,2
  fill_e0(); __syncthreads();
  agg_stage_h<1>(tp, AWt, AB, e0h[half], c); __syncthreads();
  fill_e1(); __syncthreads();
  agg_stage_h<4>(tp, AWt + 8192, AB + 128, e1h[half], c); __syncthreads();
  #pragma unroll 2
  for (int r = 0; r < 16; r++){
    float m = 0.25f*( EC[nn3[half][4*r]*128+c]   + EC[nn3[half][4*r+1]*128+c]
                    + EC[nn3[half][4*r+2]*128+c] + EC[nn3[half][4*r+3]*128+c] );
    tp[r*128 + c] = f2h(m + h2f(e2h[half][r*128 + c]));
  }
  __syncthreads();
  agg_stage_h<16>(tp, AWt + 16384, AB + 256, e2h[half], c); __syncthreads();
  // i=1: j=0,1
  fill_e0(); __syncthreads();
  agg_stage_h<1>(tp, AWt, AB, e0h[half], c); __syncthreads();
  fill_e1(); __syncthreads();
  agg_stage_h<4>(tp, AWt + 8192, AB + 128, e1h[half], c); __syncthreads();
  // i=2: j=0
  fill_e0(); __syncthreads();
  agg_stage_h<1>(tp, AWt, AB, e0h[half], c); __syncthreads();
  // agg = tanh(e0 @ ALW.T + ALB)
  agg_stage_h<1>(e0h[half], ALWt, ALB, tp, c); __syncthreads();
  EQREC[bs*128 + c] = msk ? h2f(tp[c]) : EQ[n0*128 + c];
}

// ---------------------------------------------------------------- K2: gi1 precompute (K=256, f16 dot2, coalesced)
__launch_bounds__(384, 1)
__global__ void k_gi1(const float* __restrict__ EQREC,
                      const int* __restrict__ response,
                      const float* __restrict__ ECOR,
                      const u32* __restrict__ WIH1t,
                      const float* __restrict__ BIH1,
                      float* __restrict__ GI1)
{
  const int t  = blockIdx.x;
  const int bg = blockIdx.y;
  const int tid = threadIdx.x;
  __shared__ __align__(16) u16 X[8][256];
  for (int o = tid; o < 2048; o += 384){
    int bb = o >> 8, k = o & 255;
    int b = bg*8 + bb;
    float v = (k < 128) ? EQREC[(b*S_ + t)*128 + k]
                        : ECOR[response[b*S_ + t]*128 + (k - 128)];
    X[bb][k] = f2h(v);
  }
  __syncthreads();
  float bias = BIH1[tid];
  float acc[8];
  #pragma unroll
  for (int i = 0; i < 8; i++) acc[i] = bias;
  const uint4* wp = (const uint4*)WIH1t;   // 32 groups x 384
  #pragma unroll 4
  for (int g = 0; g < 32; g++){
    uint4 wv = wp[g*384 + tid];            // coalesced
    #pragma unroll
    for (int bb = 0; bb < 8; bb++){
      uint4 hv = *(const uint4*)(&X[bb][g*8]);   // broadcast
      acc[bb] = dot2f(wv.x, hv.x, acc[bb]);
      acc[bb] = dot2f(wv.y, hv.y, acc[bb]);
      acc[bb] = dot2f(wv.z, hv.z, acc[bb]);
      acc[bb] = dot2f(wv.w, hv.w, acc[bb]);
    }
  }
  #pragma unroll
  for (int bb = 0; bb < 8; bb++)
    GI1[(t*32 + bg*8 + bb)*384 + tid] = acc[bb];
}

// ---------------------------------------------------------------- K4: FUSED h1/h2 recurrence + embedded top-k
// Chain path (blockIdx 0..31): round-5 version, proven 203us. Only 32 CUs
// are busy for those 203us -- so the former k_topk's 6368 one-wave pairs
// ride along as blocks 32..562 (12 pairs/block, one per wave, no block
// barriers in that path). Chain waves take s_setprio(1) so co-resident
// topk waves never stall the latency-critical recurrence. Chain blocks are
// first in dispatch order -> they grab CUs immediately.
__launch_bounds__(768, 3)
__global__ void k_chain12(const float* __restrict__ GI1,
                          const u16* __restrict__ WHH1h, const float* __restrict__ BHH1,
                          const u16* __restrict__ WIH2h, const float* __restrict__ BIH2,
                          const u16* __restrict__ WHH2h, const float* __restrict__ BHH2,
                          const float* __restrict__ H1I, const float* __restrict__ H2I,
                          float* __restrict__ G2,
                          const int* __restrict__ question,
                          const float* __restrict__ EQ,
                          int* __restrict__ IDX)
{
  const int tid = threadIdx.x;
  __shared__ __align__(16) u16 hh1[128];
  __shared__ __align__(16) u16 hh2[128];
  __shared__ __align__(16) float psBuf[2304];
  __shared__ __align__(16) float qns[12][128];

  if (blockIdx.x >= 32){
    // ---------------- top-k path: 12 waves, one (t,b) pair each; NO block
    // barriers (wave-lockstep + lgkmcnt only).
    const int wv = tid >> 6, lane = tid & 63;
    const int p = (blockIdx.x - 32)*12 + wv;
    if (p >= T_*B_) return;
    const int t = p >> 5, bq = p & 31;
    const int qid = question[bq*S_ + t + 1];
    float* qn = qns[wv];
    qn[lane]      = EQ[qid*128 + lane];
    qn[lane + 64] = EQ[qid*128 + 64 + lane];
    asm volatile("s_waitcnt lgkmcnt(0)" ::: "memory");
    float val[4]; int sv[4];
    #pragma unroll
    for (int i = 0; i < 4; i++){
      int s = lane + 64*i;
      sv[i] = s;
      float v = -3.0e38f;
      if (s < S_) v = (s < t) ? dot128f(EQ + question[bq*S_ + s]*128, qn) : NEGV;
      val[i] = v;
    }
    for (int r = 0; r < 10; r++){
      float bv = -3.0e38f; int bi = 0x3fffffff;
      #pragma unroll
      for (int i = 0; i < 4; i++){
        if (val[i] > bv || (val[i] == bv && sv[i] < bi)){ bv = val[i]; bi = sv[i]; }
      }
      for (int off = 32; off; off >>= 1){
        float ov = __shfl_down(bv, off);
        int   oi = __shfl_down(bi, off);
        if (ov > bv || (ov == bv && oi < bi)){ bv = ov; bi = oi; }
      }
      int win = __shfl(bi, 0);
      if (lane == 0) IDX[p*10 + r] = win;
      #pragma unroll
      for (int i = 0; i < 4; i++) if (sv[i] == win) val[i] = -3.0e38f;
    }
    return;
  }

  // ---------------- chain path (blockIdx 0..31)
  __builtin_amdgcn_s_setprio(1);
  const int b = blockIdx.x;

  int half, r0, sidx;
  const u16* wrow;
  const u16* hbase;
  float bias0, bias1, bias2;
  if (tid < 512){
    int i = tid;
    half = (i >= 256) ? 1 : 0; i -= half*256;      // wave-uniform
    r0 = 3*i;                                      // rows r0..r0+2 in [0,768)
    wrow  = ((r0 < 384) ? (WHH1h + r0*128) : (WIH2h + (r0-384)*128)) + half*64;
    hbase = hh1 + half*64;
    sidx  = half*768 + r0;
    if (half == 0){
      if (r0 < 384){ bias0 = BHH1[r0];     bias1 = BHH1[r0+1];   bias2 = BHH1[r0+2]; }
      else         { bias0 = BIH2[r0-384]; bias1 = BIH2[r0-383]; bias2 = BIH2[r0-382]; }
    } else { bias0 = bias1 = bias2 = 0.f; }
  } else {
    int j = tid - 512;
    half = (j >= 128) ? 1 : 0; j -= half*128;      // wave-uniform
    r0 = 3*j;                                      // rows in [0,384)
    wrow  = WHH2h + r0*128 + half*64;
    hbase = hh2 + half*64;
    sidx  = 1536 + half*384 + r0;
    if (half == 0){ bias0 = BHH2[r0]; bias1 = BHH2[r0+1]; bias2 = BHH2[r0+2]; }
    else { bias0 = bias1 = bias2 = 0.f; }
  }
  uint4 Wa[8], Wb[8], Wc[8];
  {
    const uint4* p0 = (const uint4*)(wrow);
    const uint4* p1 = (const uint4*)(wrow + 128);
    const uint4* p2 = (const uint4*)(wrow + 256);
    #pragma unroll
    for (int g = 0; g < 8; g++){ Wa[g] = p0[g]; Wb[g] = p1[g]; Wc[g] = p2[g]; }
  }
  #pragma unroll
  for (int g = 0; g < 8; g++){
    PINV(Wa[g].x); PINV(Wa[g].y); PINV(Wa[g].z); PINV(Wa[g].w);
    PINV(Wb[g].x); PINV(Wb[g].y); PINV(Wb[g].z); PINV(Wb[g].w);
    PINV(Wc[g].x); PINV(Wc[g].y); PINV(Wc[g].z); PINV(Wc[g].w);
  }

  auto mv = [&](){
    float a0 = bias0, a1 = bias1, a2 = bias2;
    #pragma unroll
    for (int g = 0; g < 8; g++){
      uint4 hv = *(const uint4*)(hbase + g*8);    // uniform b128 (broadcast)
      a0 = dot2f(Wa[g].x, hv.x, a0); a0 = dot2f(Wa[g].y, hv.y, a0);
      a0 = dot2f(Wa[g].z, hv.z, a0); a0 = dot2f(Wa[g].w, hv.w, a0);
      a1 = dot2f(Wb[g].x, hv.x, a1); a1 = dot2f(Wb[g].y, hv.y, a1);
      a1 = dot2f(Wb[g].z, hv.z, a1); a1 = dot2f(Wb[g].w, hv.w, a1);
      a2 = dot2f(Wc[g].x, hv.x, a2); a2 = dot2f(Wc[g].y, hv.y, a2);
      a2 = dot2f(Wc[g].z, hv.z, a2); a2 = dot2f(Wc[g].w, hv.w, a2);
    }
    psBuf[sidx] = a0; psBuf[sidx+1] = a1; psBuf[sidx+2] = a2;
  };

  float h1c = 0.f, h2c = 0.f;
  float pc0 = 0.f, pc1 = 0.f, pc2 = 0.f;   // gi1 regs, live in tid [128,256)
  if (tid < 128){
    h2c = H2I[b*128 + tid]; hh2[tid] = f2h(h2c);
  } else if (tid < 256){
    int u = tid - 128;
    h1c = H1I[b*128 + u]; hh1[u] = f2h(h1c);
    const float* gp = GI1 + b*384;         // gi1(0)
    pc0 = gp[u]; pc1 = gp[128+u]; pc2 = gp[256+u];
  }
  BARX();

  // prologue: h1(1) = gru1(x0, h1(0)); C/D partials written here are junk
  // and are overwritten before first read.
  mv();
  BARX();
  if (tid >= 128 && tid < 256){
    int u = tid - 128;
    float r = fast_sigmoid(pc0 + psBuf[u]     + psBuf[768+u]);
    float z = fast_sigmoid(pc1 + psBuf[128+u] + psBuf[896+u]);
    float n = fast_tanh(pc2 + r*(psBuf[256+u] + psBuf[1024+u]));
    h1c = (1.f - z)*n + z*h1c;
    hh1[u] = f2h(h1c);
    const float* gp = GI1 + (32 + b)*384;  // gi1(1)
    pc0 = gp[u]; pc1 = gp[128+u]; pc2 = gp[256+u];
  }
  BARX();

  float* gout = G2 + b*128 + tid;          // dereferenced only for tid<128
  #pragma unroll 1
  for (int t = 0; t < T_; t++){
    // prefetch gi1(t+2) (consumed next iteration; hidden under matvec)
    float pn0 = 0.f, pn1 = 0.f, pn2 = 0.f;
    if (tid >= 128 && tid < 256){
      int u = tid - 128;
      int tp = (t + 2 < T_) ? t + 2 : T_ - 1;
      const float* gp = GI1 + (tp*32 + b)*384;
      pn0 = gp[u]; pn1 = gp[128+u]; pn2 = gp[256+u];
    }
    mv();   // a = WHH1@h1(t+1), c = WIH2@h1(t+1), d = WHH2@h2carry
    BARX();
    if (tid < 128){
      // GRU2: g2(t) = gru2(h1(t+1), h2carry)
      float cs0 = psBuf[384+tid]  + psBuf[1152+tid];
      float cs1 = psBuf[512+tid]  + psBuf[1280+tid];
      float cs2 = psBuf[640+tid]  + psBuf[1408+tid];
      float ds0 = psBuf[1536+tid] + psBuf[1920+tid];
      float ds1 = psBuf[1664+tid] + psBuf[2048+tid];
      float ds2 = psBuf[1792+tid] + psBuf[2176+tid];
      float r2 = fast_sigmoid(cs0 + ds0);
      float z2 = fast_sigmoid(cs1 + ds1);
      float n2 = fast_tanh(cs2 + r2*ds2);
      float g  = (1.f - z2)*n2 + z2*h2c;
      gout[t*4096] = g;                    // G2[(t*32+b)*128+tid]
      if (t > 0) h2c = g;                  // reference: h2 carry frozen at t==0
      hh2[tid] = f2h(h2c);
    } else if (tid < 256){
      // GRU1: h1(t+2) = gru1(x_{t+1}, h1(t+1))
      int u = tid - 128;
      float as0 = psBuf[u]     + psBuf[768+u];
      float as1 = psBuf[128+u] + psBuf[896+u];
      float as2 = psBuf[256+u] + psBuf[1024+u];
      float r1 = fast_sigmoid(pc0 + as0);
      float z1 = fast_sigmoid(pc1 + as1);
      float n1 = fast_tanh(pc2 + r1*as2);
      h1c = (1.f - z1)*n1 + z1*h1c;
      hh1[u] = f2h(h1c);
    }
    pc0 = pn0; pc1 = pn1; pc2 = pn2;
    BARX();
  }
}

// ---------------------------------------------------------------- K5: Kp·w_k for all G2 rows (coalesced QWt)
__launch_bounds__(128, 4)
__global__ void k_kp(const float* __restrict__ G2,
                     const float* __restrict__ QWt, const float* __restrict__ QB,
                     const float* __restrict__ MW,
                     float* __restrict__ KPWG)
{
  __shared__ __align__(16) float X[8][128];
  __shared__ float red[8][2];
  const int tid = threadIdx.x;           // c in [0,128)
  const int base = blockIdx.x * 8;       // 796 blocks x 8 rows = 6368
  for (int o = tid; o < 1024; o += 128){
    int r = o >> 7, c = o & 127;
    X[r][c] = G2[(base + r)*128 + c];
  }
  __syncthreads();
  float acc[8];
  float bias = QB[tid];
  #pragma unroll
  for (int r = 0; r < 8; r++) acc[r] = bias;
  const float4* wp = (const float4*)QWt;   // 32 groups x 128
  #pragma unroll 4
  for (int g = 0; g < 32; g++){
    float4 wv = wp[g*128 + tid];           // coalesced
    int kk = 4*g;
    #pragma unroll
    for (int r = 0; r < 8; r++){
      float4 t4 = *(const float4*)(&X[r][kk]);
      acc[r] = fmaf(t4.x, wv.x, acc[r]);
      acc[r] = fmaf(t4.y, wv.y, acc[r]);
      acc[r] = fmaf(t4.z, wv.z, acc[r]);
      acc[r] = fmaf(t4.w, wv.w, acc[r]);
    }
  }
  const float wk = MW[128 + tid];
  const int lane = tid & 63, wv_ = tid >> 6;
  #pragma unroll
  for (int r = 0; r < 8; r++){
    float pv = fast_tanh(acc[r]) * wk;
    for (int off = 32; off; off >>= 1) pv += __shfl_down(pv, off);
    if (lane == 0) red[r][wv_] = pv;
  }
  __syncthreads();
  if (tid < 8) KPWG[base + tid] = red[tid][0] + red[tid][1];
}

// ---------------------------------------------------------------- K6: predict + output
__global__ void k_pred(const int* __restrict__ question,
                       const int* __restrict__ qci, const void* __restrict__ qcm,
                       const int* __restrict__ flags,
                       const float* __restrict__ EQ, const float* __restrict__ EC,
                       const float* __restrict__ QB, const float* __restrict__ MW,
                       const float* __restrict__ G2,
                       const int* __restrict__ IDX,
                       const float* __restrict__ KPWG,
                       void* __restrict__ outp)
{
  const int blk = blockIdx.x;
  const int t = blk >> 5, b = blk & 31;
  const int tid = threadIdx.x;               // 64
  __shared__ float hist[11][132];
  __shared__ float qcs[128];
  __shared__ float og[11];
  __shared__ float kpw[11];
  __shared__ int   idxs[10];
  __shared__ float kpw0s;
  const int qid = question[b*S_ + t + 1];
  const int bflag = flags[1];
  if (tid < 10) idxs[tid] = IDX[blk*10 + tid];
  __syncthreads();
  for (int o = tid; o < 11*128; o += 64){
    int k = o >> 7, c = o & 127;
    float v;
    if (k == 0) v = G2[blk*128 + c];
    else { int s = idxs[k-1]; v = (s == 0) ? 0.f : G2[(s*32 + b)*128 + c]; }
    hist[k][c] = v;
  }
  #pragma unroll
  for (int o = tid; o < 128; o += 64){
    float v = EQ[qid*128 + o];
    #pragma unroll
    for (int q = 0; q < 4; q++){
      if (readBool(qcm, qid*4 + q, bflag))
        v += EC[qci[qid*4 + q]*128 + o];
    }
    qcs[o] = v;
  }
  {
    float pv = fast_tanh(QB[tid])      * MW[128 + tid]
             + fast_tanh(QB[tid + 64]) * MW[128 + tid + 64];
    for (int off = 32; off; off >>= 1) pv += __shfl_down(pv, off);
    if (tid == 0) kpw0s = pv;
  }
  __syncthreads();
  if (tid < 11){
    float acc = 0.f;
    for (int c = 0; c < 128; c++) acc = fmaf(qcs[c], hist[tid][c], acc);
    og[tid] = acc;
    float v;
    if (tid == 0) v = KPWG[blk];
    else { int s = idxs[tid-1]; v = (s == 0) ? kpw0s : KPWG[s*32 + b]; }
    kpw[tid] = v;
  }
  __syncthreads();
  if (tid == 0){
    float tv[11];
    #pragma unroll
    for (int k = 0; k < 11; k++){
      int valid = (k == 0) || (idxs[k-1] < t);
      tv[k] = valid ? kpw[k] : NEGV;
    }
    float m = tv[0];
    #pragma unroll
    for (int k = 1; k < 11; k++) m = fmaxf(m, tv[k]);
    float den = 0.f, num = 0.f;
    #pragma unroll
    for (int k = 0; k < 11; k++){
      float e = __expf(tv[k] - m);
      den += e;
      num = fmaf(e, og[k], num);
    }
    float p = num / den;
    int col = (t == 0) ? 0 : (t + 1);
    if (flags[0]){
      ((float*)outp)[b*S_ + col] = p;
      if (t == 0) ((float*)outp)[b*S_ + 1] = 0.f;
    } else {
      ((u16*)outp)[b*S_ + col] = f2bf(p);
      if (t == 0) ((u16*)outp)[b*S_ + 1] = (u16)0;
    }
  }
}

// ---------------------------------------------------------------- launcher
extern "C" void kernel_launch(void* const* d_in, const int* in_sizes, int n_in,
                              void* d_out, int out_size, void* d_ws, size_t ws_size,
                              hipStream_t stream)
{
  (void)in_sizes; (void)n_in; (void)out_size; (void)ws_size;
  const int* question      = (const int*)d_in[0];
  const int* response      = (const int*)d_in[1];
  const void* maskp        = d_in[2];
  const int* q_neighbors   = (const int*)d_in[3];
  const int* s_neighbors   = (const int*)d_in[4];
  const int* q_concept_idx = (const int*)d_in[5];
  const void* q_concept_mask = d_in[6];

  static const int CN[NCVT] = {2560000,256000,256,98304,49152,384,384,49152,49152,
                               384,384,49152,384,16384,128,16384,128,16384,128,
                               256,1,4096,4096};
  CvtArgs ca;
  int off = 0;
  for (int i = 0; i < NCVT; i++){
    ca.s[i] = d_in[7 + i];
    ca.nreal[i] = CN[i];
    ca.off[i] = off;
    off += (CN[i] + 3) & ~3;
  }
  ca.off[NCVT] = off;
  const int total = off;

  char* ws = (char*)d_ws;
  size_t wo = 0;
  auto alloc = [&](size_t bytes) -> void* {
    void* p = ws + wo;
    wo = (wo + bytes + 255) & ~(size_t)255;
    return p;
  };
  int*   flags = (int*)  alloc(16);
  float* CVT   = (float*)alloc((size_t)total * 4);
  float* EQREC = (float*)alloc((size_t)B_*S_*D_*4);
  float* GI1   = (float*)alloc((size_t)T_*B_*384*4);
  float* G2    = (float*)alloc((size_t)T_*B_*D_*4);
  int*   IDX   = (int*)  alloc((size_t)T_*B_*10*4);
  float* KPWG  = (float*)alloc((size_t)T_*B_*4);
  u16*   WHH1h = (u16*)  alloc(49152*2);
  u16*   WHH2h = (u16*)  alloc(49152*2);
  u16*   WIH2h = (u16*)  alloc(49152*2);
  u32*   AWt   = (u32*)  alloc(24576*4);
  u32*   ALWt  = (u32*)  alloc(8192*4);
  u32*   WIH1t = (u32*)  alloc(49152*4);
  float* QWt   = (float*)alloc(16384*4);

  const float* EQ   = CVT + ca.off[0];
  const float* EC   = CVT + ca.off[1];
  const float* ECOR = CVT + ca.off[2];
  const float* WIH1 = CVT + ca.off[3];
  const float* WHH1 = CVT + ca.off[4];
  const float* BIH1 = CVT + ca.off[5];
  const float* BHH1 = CVT + ca.off[6];
  const float* WIH2 = CVT + ca.off[7];
  const float* WHH2 = CVT + ca.off[8];
  const float* BIH2 = CVT + ca.off[9];
  const float* BHH2 = CVT + ca.off[10];
  const float* AW   = CVT + ca.off[11];
  const float* AB   = CVT + ca.off[12];
  const float* ALW  = CVT + ca.off[13];
  const float* ALB  = CVT + ca.off[14];
  const float* QW   = CVT + ca.off[15];
  const float* QB   = CVT + ca.off[16];
  const float* MW   = CVT + ca.off[19];
  const float* H1I  = CVT + ca.off[21];
  const float* H2I  = CVT + ca.off[22];

  const int TOPK_BLOCKS = (T_*B_ + 11) / 12;   // 531

  k_sniff2<<<1, 256, 0, stream>>>((const u16*)d_in[7], (const unsigned char*)maskp, flags);
  k_cvt<<<(total + 255)/256, 256, 0, stream>>>(ca, flags, CVT);
  k_prep<<<192, 256, 0, stream>>>(WHH1, WHH2, AW, ALW, WIH1, WIH2, QW,
                                  WHH1h, WHH2h, WIH2h, AWt, ALWt, WIH1t, QWt);
  k_agg<<<B_*S_/2, 256, 0, stream>>>(question, q_neighbors, s_neighbors, EQ, EC,
                                     AWt, AB, ALWt, ALB, maskp, flags, EQREC);
  k_gi1<<<dim3(T_, 4), 384, 0, stream>>>(EQREC, response, ECOR, WIH1t, BIH1, GI1);
  k_chain12<<<32 + TOPK_BLOCKS, 768, 0, stream>>>(GI1, WHH1h, BHH1, WIH2h, BIH2,
                                                  WHH2h, BHH2, H1I, H2I, G2,
                                                  question, EQ, IDX);
  k_kp<<<T_*B_/8, 128, 0, stream>>>(G2, QWt, QB, MW, KPWG);
  k_pred<<<T_*B_, 64, 0, stream>>>(question, q_concept_idx, q_concept_mask, flags,
                                   EQ, EC, QB, MW, G2, IDX, KPWG, d_out);
}